// Round 3
// baseline (277.949 us; speedup 1.0000x reference)
//
#include <hip/hip_runtime.h>

// B=4, CIN=COUT=64, H=W=128, 3x3 deformable conv, fp32 in/out.
// R15 = R14 fast path + tile-level pipelining:
//  - dcn_fused: 512 blocks x 2 tiles each, double-buffered halo staging.
//    Tile t+1's global_load_lds staging (32 KB, no VGPR cost) is issued at
//    the start of tile t's compute -> staging latency hides under stage-1/2.
//  - buffer stride 32768 (staging fits exactly; no spill into offl -> no
//    async-write race with stage-1's offl scatter).
//  - LDS 70144 B (2 x 32768 + offl 4608) via dynamic shared memory +
//    hipFuncSetAttribute (gfx950 allows >64 KB/workgroup). If the attribute
//    call fails, fall back to the harness-proven R12 path.
//  - 2 blocks/CU (vs 4): trades TLP for explicit cross-tile overlap.

typedef __attribute__((ext_vector_type(8))) short short8x;
typedef __attribute__((ext_vector_type(4))) float float4x;
typedef unsigned short ushort;
typedef unsigned int uint;

__device__ __forceinline__ ushort f2bf(float f) {
    uint b = __float_as_uint(f);
    b += 0x7fffu + ((b >> 16) & 1u);
    return (ushort)(b >> 16);
}
__device__ __forceinline__ float bf2f(ushort u) {
    return __uint_as_float(((uint)u) << 16);
}

__device__ __forceinline__ void gload16(const void* g, void* l) {
    __builtin_amdgcn_global_load_lds(
        (const __attribute__((address_space(1))) void*)g,
        (__attribute__((address_space(3))) void*)l, 16, 0, 0);
}

// ===========================================================================
// FAST PATH (requires ws_size >= 8.5 MB and >64KB dynamic LDS support)
// ===========================================================================

// ---------------------------------------------------------------------------
// Prologue (one kernel, 944 blocks x 128):
//  blocks [0,512):   x (b,c,y,x) fp32 -> xbf (b,y,x,c) bf16. Thread = pixel.
//  blocks [512,944): weight packing into MFMA B-fragment order (R5 layout).
//  zero page: 16 B of zeros for OOB staging lanes.
// ---------------------------------------------------------------------------
__global__ __launch_bounds__(128) void pack_all(
    const float* __restrict__ x, const float* __restrict__ w_def,
    const float* __restrict__ w_off, ushort* __restrict__ xbf,
    ushort* __restrict__ Bd, ushort* __restrict__ Bo, uint* __restrict__ zp) {
    int tid = threadIdx.x, bid = blockIdx.x;
    if (bid < 512) {
        int p = (bid << 7) + tid;          // 0..65535 pixel id
        if (p == 0) { zp[0] = 0; zp[1] = 0; zp[2] = 0; zp[3] = 0; }
        int b = p >> 14;
        const float* src = x + ((long)b << 20) + (p & 16383);
        ushort* dst = xbf + ((long)p << 6);
        float v[64];
#pragma unroll
        for (int c = 0; c < 64; ++c) v[c] = src[(long)c << 14];
#pragma unroll
        for (int g = 0; g < 8; ++g) {
            uint4 d;
            d.x = (uint)f2bf(v[g * 8 + 0]) | ((uint)f2bf(v[g * 8 + 1]) << 16);
            d.y = (uint)f2bf(v[g * 8 + 2]) | ((uint)f2bf(v[g * 8 + 3]) << 16);
            d.z = (uint)f2bf(v[g * 8 + 4]) | ((uint)f2bf(v[g * 8 + 5]) << 16);
            d.w = (uint)f2bf(v[g * 8 + 6]) | ((uint)f2bf(v[g * 8 + 7]) << 16);
            *(uint4*)(dst + (g << 3)) = d;
        }
    } else {
        int idx = ((bid - 512) << 7) + tid;   // 0..55295
        if (idx < 36864) {
            int i = idx & 7;
            int lane = (idx >> 3) & 63;
            int nt = (idx >> 9) & 3;
            int kk = idx >> 11;
            int n = (nt << 4) + (lane & 15);
            int k2 = kk >> 1;
            int cin = ((kk & 1) << 5) + ((lane >> 4) << 3) + i;
            Bd[idx] = f2bf(w_def[(n * 64 + cin) * 9 + k2]);
        } else {
            int d = idx - 36864;
            int i = d & 7;
            int lane = (d >> 3) & 63;
            int nt = (d >> 9) & 1;
            int kk = d >> 10;
            int n = (nt << 4) + (lane & 15);
            int k2 = kk >> 1;
            int cin = ((kk & 1) << 5) + ((lane >> 4) << 3) + i;
            Bo[d] = (n < 18) ? f2bf(w_off[(n * 64 + cin) * 9 + k2]) : (ushort)0;
        }
    }
}

// ---------------------------------------------------------------------------
// Fused kernel (fast path). 512 blocks x 512 threads; block = 2 tiles of
// 8x8 pixels, double-buffered. wq = wv&3 owns pixels 16wq..16wq+15;
// half = wv>>2 owns cins 32half..+31 (and n-group half in stage 1).
// Dynamic LDS 70144 B: buf0 [0,32768) | buf1 [32768,65536) | offl 4608 B.
// red[64][65] (16640 B) overlays the CURRENT tile's buffer in the epilogue.
// ---------------------------------------------------------------------------
__global__ __launch_bounds__(512, 4) void dcn_fused(
    const float* __restrict__ x, const ushort* __restrict__ xbf,
    const ushort* __restrict__ Bd, const ushort* __restrict__ Bo,
    const float* __restrict__ boff, const float* __restrict__ bdef,
    const ushort* __restrict__ zp, float* __restrict__ out) {

    extern __shared__ __align__(16) char smem[];
    float* offl = (float*)(smem + 65536);      // [px 64][ch 18]

    int tid = threadIdx.x;
    int lane = tid & 63, wv = tid >> 6;
    int wq = wv & 3, half = wv >> 2;
    // XCD-aware swizzle: 512 blocks % 8 == 0 -> bijective. XCD k gets a
    // contiguous run of 64 blocks = 128 adjacent tiles.
    int raw = blockIdx.x;
    int blk = ((raw & 7) << 6) + (raw >> 3);
    int tile0 = blk << 1;                      // tiles {tile0, tile0+1}

    const ushort* xb2base = xbf;

    // ---- staging helper: 32 chunks x 1 KiB via global_load_lds dwordx4.
    // LDS byte o = chunk*1024 + lane*16; pos = (o/16)/9, slot = (o/16)%9.
    // slot<8 -> cins 8*slot.. of pixel (th0-3+ty, tw0-3+tx); slot==8 (row
    // pad), OOB rows and fake pos>=225 -> zero page. Writes [0,32768) of
    // dst exactly (no spill).
    auto stage_tile = [&](int tile_i, char* dst) {
        int tb = tile_i >> 8, tq = tile_i & 255;
        int th0 = (tq >> 4) << 3, tw0 = (tq & 15) << 3;
        const ushort* xb2 = xb2base + ((long)tb << 20);
#pragma unroll
        for (int c = 0; c < 4; ++c) {
            int chunk = wv + (c << 3);
            int o4 = (chunk << 6) + lane;           // byte/16, 0..2047
            int pos = (o4 * 7282) >> 16;            // /9 (exact)
            int slot = o4 - pos * 9;
            int ty = (pos * 4370) >> 16;            // /15 (exact)
            int tx = pos - ty * 15;
            int y = th0 - 3 + ty, xx = tw0 - 3 + tx;
            bool valid = ((unsigned)y < 128u) & ((unsigned)xx < 128u)
                       & (slot < 8) & (pos < 225);
            const ushort* gp = valid
                ? xb2 + (((y << 7) + xx) << 6) + (slot << 3)
                : zp;
            gload16(gp, dst + (chunk << 10));
        }
    };

    int l15 = lane & 15, lq = lane >> 4;
    int p1 = (wq << 4) + l15;          // this lane's A-row pixel
    int plh = p1 >> 3, plw = p1 & 7;

    // ---- prologue: stage tile0 into buf0, wait.
    stage_tile(tile0, smem);
    __syncthreads();

    for (int tt = 0; tt < 2; ++tt) {
        char* bufc = smem + (tt << 15);
        ushort* tile = (ushort*)bufc;          // [pos(225) stride 72][cin 64]
        int ti = tile0 + tt;
        int b = ti >> 8, t = ti & 255;
        int h0 = (t >> 4) << 3, w0 = (t & 15) << 3;
        const float* xb = x + ((long)b << 20);

        // ---- prefetch next tile into buf1 (async; latency hides under
        // stage-1/2; drained by the post-stage-1 barrier's vmcnt(0)).
        if (tt == 0) stage_tile(tile0 + 1, smem + 32768);

        // ---- stage 1: offset conv via MFMA, N-split.
        float4x oacc = {0.f, 0.f, 0.f, 0.f};
#pragma unroll
        for (int k2 = 0; k2 < 9; ++k2) {
            int kh = k2 / 3, kw = k2 - kh * 3;
            int pos = (plh + 2 + kh) * 15 + (plw + 2 + kw);
            int abase = pos * 72 + (lq << 3);
#pragma unroll
            for (int hf = 0; hf < 2; ++hf) {
                int kk = k2 * 2 + hf;
                short8x a = *(const short8x*)&tile[abase + hf * 32];
                short8x bo = *(const short8x*)&Bo[(kk * 2 + half) * 512 + (lane << 3)];
                oacc = __builtin_amdgcn_mfma_f32_16x16x32_bf16(a, bo, oacc, 0, 0, 0);
            }
        }
        {   // scatter D (col n = 16*half + l15, row = lq*4+r) + bias -> offl
            int n = (half << 4) + l15;
            if (n < 18) {
                float bo = boff[n];
#pragma unroll
                for (int r = 0; r < 4; ++r) {
                    int p = (wq << 4) + (lq << 2) + r;
                    offl[p * 18 + n] = oacc[r] + bo;
                }
            }
        }
        __syncthreads();

        // ---- offsets to registers (constant-indexed only) + oob mask
        float2 offr[9];
        uint oobmask = 0;
#pragma unroll
        for (int k2 = 0; k2 < 9; ++k2) {
            offr[k2] = *(const float2*)&offl[p1 * 18 + k2 * 2];
            const int kh = k2 / 3, kw = k2 - kh * 3;
            float sy = (float)(plh + 2 + kh) + offr[k2].x;
            float sx = (float)(plw + 2 + kw) + offr[k2].y;
            int by = (int)floorf(sy), bx = (int)floorf(sx);
            bool oob = ((unsigned)by > 13u) | ((unsigned)bx > 13u);
            oobmask |= oob ? (1u << k2) : 0u;
        }

        // ---- stage 2: 9 steps over this wave's cin-half
        float4x acc[4];
#pragma unroll
        for (int nt = 0; nt < 4; ++nt) acc[nt] = (float4x){0.f, 0.f, 0.f, 0.f};

#pragma unroll
        for (int k2 = 0; k2 < 9; ++k2) {
            const int kh = k2 / 3, kw = k2 - kh * 3;
            float sy = (float)(plh + 2 + kh) + offr[k2].x;
            float sx = (float)(plw + 2 + kw) + offr[k2].y;
            float yf = floorf(sy), xf = floorf(sx);
            int by = (int)yf, bx = (int)xf;
            float wy1 = sy - yf, wx1 = sx - xf;
            float wy0 = 1.f - wy1, wx0 = 1.f - wx1;
            float w00 = wy0 * wx0, w01 = wy0 * wx1;
            float w10 = wy1 * wx0, w11 = wy1 * wx1;
            int byc = min(max(by, 0), 13), bxc = min(max(bx, 0), 13);
            int cb = (byc * 15 + bxc) * 72 + (lq << 3) + (half << 5);

            int kk = k2 * 2 + half;
            short8x c00 = *(const short8x*)&tile[cb];
            short8x c01 = *(const short8x*)&tile[cb + 72];
            short8x c10 = *(const short8x*)&tile[cb + 72 * 15];
            short8x c11 = *(const short8x*)&tile[cb + 72 * 16];
            float s[8];
#pragma unroll
            for (int j = 0; j < 8; ++j) {
                s[j] = w00 * bf2f((ushort)c00[j]) + w01 * bf2f((ushort)c01[j])
                     + w10 * bf2f((ushort)c10[j]) + w11 * bf2f((ushort)c11[j]);
            }
            union { short8x v; ushort u[8]; } A;
#pragma unroll
            for (int j = 0; j < 8; ++j) A.u[j] = f2bf(s[j]);
#pragma unroll
            for (int nt = 0; nt < 4; ++nt) {
                short8x bw = *(const short8x*)&Bd[(kk * 4 + nt) * 512 + (lane << 3)];
                acc[nt] = __builtin_amdgcn_mfma_f32_16x16x32_bf16(A.v, bw, acc[nt], 0, 0, 0);
            }
        }

        // ---- cold exactness pass (own half): out-of-tile samples (~8 sigma,
        // never taken on this data).
        if (__any(oobmask != 0)) {
#pragma unroll 1
            for (int k2 = 0; k2 < 9; ++k2) {
                if (!__any((oobmask >> k2) & 1)) continue;
                bool oob = (oobmask >> k2) & 1;
                const int kh = k2 / 3, kw = k2 - kh * 3;
                float2 od = *(const float2*)&offl[p1 * 18 + k2 * 2];
                float sy = (float)(plh + 2 + kh) + od.x;
                float sx = (float)(plw + 2 + kw) + od.y;
                float yf = floorf(sy), xf = floorf(sx);
                int by = (int)yf, bx = (int)xf;
                float wy1 = sy - yf, wx1 = sx - xf;
                float wy0 = 1.f - wy1, wx0 = 1.f - wx1;
                float w00 = wy0 * wx0, w01 = wy0 * wx1;
                float w10 = wy1 * wx0, w11 = wy1 * wx1;
                int byc = min(max(by, 0), 13), bxc = min(max(bx, 0), 13);
                int cb = (byc * 15 + bxc) * 72 + (lq << 3) + (half << 5);
                int y0g = by + h0 - 3, x0g = bx + w0 - 3;
                int y1g = y0g + 1, x1g = x0g + 1;
                float m00 = ((unsigned)y0g < 128u && (unsigned)x0g < 128u) ? w00 : 0.f;
                float m01 = ((unsigned)y0g < 128u && (unsigned)x1g < 128u) ? w01 : 0.f;
                float m10 = ((unsigned)y1g < 128u && (unsigned)x0g < 128u) ? w10 : 0.f;
                float m11 = ((unsigned)y1g < 128u && (unsigned)x1g < 128u) ? w11 : 0.f;
                int y0c = min(max(y0g, 0), 127), y1c = min(max(y1g, 0), 127);
                int x0c = min(max(x0g, 0), 127), x1c = min(max(x1g, 0), 127);
                int i00 = (y0c << 7) + x0c, i01 = (y0c << 7) + x1c;
                int i10 = (y1c << 7) + x0c, i11 = (y1c << 7) + x1c;
                int kk = k2 * 2 + half;
                int cin0 = (half << 5) + (lq << 3);
                short8x c00 = *(const short8x*)&tile[cb];
                short8x c01 = *(const short8x*)&tile[cb + 72];
                short8x c10 = *(const short8x*)&tile[cb + 72 * 15];
                short8x c11 = *(const short8x*)&tile[cb + 72 * 16];
                float d[8];
#pragma unroll
                for (int j = 0; j < 8; ++j) {
                    float sl = w00 * bf2f((ushort)c00[j]) + w01 * bf2f((ushort)c01[j])
                             + w10 * bf2f((ushort)c10[j]) + w11 * bf2f((ushort)c11[j]);
                    const float* xp = xb + ((long)(cin0 + j) << 14);
                    float sg = m00 * xp[i00] + m01 * xp[i01]
                             + m10 * xp[i10] + m11 * xp[i11];
                    d[j] = oob ? (sg - sl) : 0.f;
                }
                union { short8x v; ushort u[8]; } A;
#pragma unroll
                for (int j = 0; j < 8; ++j) A.u[j] = f2bf(d[j]);
#pragma unroll
                for (int nt = 0; nt < 4; ++nt) {
                    short8x bw = *(const short8x*)&Bd[(kk * 4 + nt) * 512 + (lane << 3)];
                    acc[nt] = __builtin_amdgcn_mfma_f32_16x16x32_bf16(A.v, bw, acc[nt], 0, 0, 0);
                }
            }
        }

        // ---- reduce half pairs through LDS red[64][65] overlaying the
        // CURRENT buffer (dead after stage-2; next tile lives in the other).
        __syncthreads();
        float* red = (float*)bufc;
        if (half == 1) {
#pragma unroll
            for (int nt = 0; nt < 4; ++nt)
#pragma unroll
                for (int r = 0; r < 4; ++r) {
                    int p = (wq << 4) + (lq << 2) + r;
                    red[p * 65 + (nt << 4) + l15] = acc[nt][r];
                }
        }
        __syncthreads();
        if (half == 0) {
#pragma unroll
            for (int nt = 0; nt < 4; ++nt)
#pragma unroll
                for (int r = 0; r < 4; ++r) {
                    int p = (wq << 4) + (lq << 2) + r;
                    red[p * 65 + (nt << 4) + l15] += acc[nt][r];
                }
        }
        __syncthreads();

        // ---- store: 512 threads, thread = (cout n, row q); 2x float4
        {
            int n = tid >> 3, q = tid & 7;
            float bd = bdef[n];
            float* dst = out + (((long)(b * 64 + n)) << 14) + ((h0 + q) << 7) + w0;
            float v[8];
#pragma unroll
            for (int c = 0; c < 8; ++c) v[c] = red[(q * 8 + c) * 65 + n] + bd;
            float4x s0 = {v[0], v[1], v[2], v[3]};
            float4x s1 = {v[4], v[5], v[6], v[7]};
            *(float4x*)(dst) = s0;
            *(float4x*)(dst + 4) = s1;
        }
        // Seam safety: next iteration's first touches are buf1 ds_reads
        // (staged + drained) and offl writes (all waves are past this tile's
        // reduce barriers, so cold-pass offl reads are complete).
    }
}

// ===========================================================================
// FALLBACK PATH (verbatim R12, harness-proven at 110.4 µs; needs ~111 KB ws)
// ===========================================================================

__global__ __launch_bounds__(256) void pack_weights(
    const float* __restrict__ w_def, const float* __restrict__ w_off,
    ushort* __restrict__ Bd, ushort* __restrict__ Bo) {
    int idx = blockIdx.x * 256 + threadIdx.x;
    if (idx < 36864) {
        int i = idx & 7;
        int lane = (idx >> 3) & 63;
        int nt = (idx >> 9) & 3;
        int kk = idx >> 11;
        int n = (nt << 4) + (lane & 15);
        int k2 = kk >> 1;
        int cin = ((kk & 1) << 5) + ((lane >> 4) << 3) + i;
        Bd[idx] = f2bf(w_def[(n * 64 + cin) * 9 + k2]);
    } else if (idx < 36864 + 18432) {
        int d = idx - 36864;
        int i = d & 7;
        int lane = (d >> 3) & 63;
        int nt = (d >> 9) & 1;
        int kk = d >> 10;
        int n = (nt << 4) + (lane & 15);
        int k2 = kk >> 1;
        int cin = ((kk & 1) << 5) + ((lane >> 4) << 3) + i;
        Bo[d] = (n < 18) ? f2bf(w_off[(n * 64 + cin) * 9 + k2]) : (ushort)0;
    }
}

__global__ __launch_bounds__(512, 4) void dcn_fused_fb(
    const float* __restrict__ x, const ushort* __restrict__ Bd,
    const ushort* __restrict__ Bo, const float* __restrict__ boff,
    const float* __restrict__ bdef, float* __restrict__ out) {

    int tid = threadIdx.x;
    int lane = tid & 63, wv = tid >> 6;
    int wq = wv & 3, half = wv >> 2;
    int blk = blockIdx.x;
    int b = blk >> 8, t = blk & 255;
    int h0 = (t >> 4) << 3, w0 = (t & 15) << 3;

    __shared__ __align__(16) char smem[37008];
    ushort* tile = (ushort*)smem;
    float* offl = (float*)(smem + 32400);

    const float* xb = x + ((long)b << 20);

    if (tid < 450) {
        int pos = tid >> 1, ch = (tid & 1) << 5;
        int ty = pos / 15, tx = pos - ty * 15;
        int y = h0 - 3 + ty, xx = w0 - 3 + tx;
        bool valid = ((unsigned)y < 128u) & ((unsigned)xx < 128u);
        int yc = min(max(y, 0), 127), xc = min(max(xx, 0), 127);
        const float* gp = xb + ((long)ch << 14) + (yc << 7) + xc;
        uint4* trow = (uint4*)&tile[pos * 72 + ch];
#pragma unroll
        for (int c8 = 0; c8 < 4; ++c8) {
            const float* g8 = gp + (c8 << 17);
            float v[8];
#pragma unroll
            for (int j = 0; j < 8; ++j) v[j] = valid ? g8[j << 14] : 0.f;
            uint4 d;
            d.x = (uint)f2bf(v[0]) | ((uint)f2bf(v[1]) << 16);
            d.y = (uint)f2bf(v[2]) | ((uint)f2bf(v[3]) << 16);
            d.z = (uint)f2bf(v[4]) | ((uint)f2bf(v[5]) << 16);
            d.w = (uint)f2bf(v[6]) | ((uint)f2bf(v[7]) << 16);
            trow[c8] = d;
        }
    }
    __syncthreads();

    int l15 = lane & 15, lq = lane >> 4;
    int p1 = (wq << 4) + l15;
    int plh = p1 >> 3, plw = p1 & 7;

    float4x oacc = {0.f, 0.f, 0.f, 0.f};
#pragma unroll
    for (int k2 = 0; k2 < 9; ++k2) {
        int kh = k2 / 3, kw = k2 - kh * 3;
        int pos = (plh + 2 + kh) * 15 + (plw + 2 + kw);
        int abase = pos * 72 + (lq << 3);
#pragma unroll
        for (int hf = 0; hf < 2; ++hf) {
            int kk = k2 * 2 + hf;
            short8x a = *(const short8x*)&tile[abase + hf * 32];
            short8x bo = *(const short8x*)&Bo[(kk * 2 + half) * 512 + (lane << 3)];
            oacc = __builtin_amdgcn_mfma_f32_16x16x32_bf16(a, bo, oacc, 0, 0, 0);
        }
    }
    {
        int n = (half << 4) + l15;
        if (n < 18) {
            float bo = boff[n];
#pragma unroll
            for (int r = 0; r < 4; ++r) {
                int p = (wq << 4) + (lq << 2) + r;
                offl[p * 18 + n] = oacc[r] + bo;
            }
        }
    }
    __syncthreads();

    float2 offr[9];
    uint oobmask = 0;
#pragma unroll
    for (int k2 = 0; k2 < 9; ++k2) {
        offr[k2] = *(const float2*)&offl[p1 * 18 + k2 * 2];
        const int kh = k2 / 3, kw = k2 - kh * 3;
        float sy = (float)(plh + 2 + kh) + offr[k2].x;
        float sx = (float)(plw + 2 + kw) + offr[k2].y;
        int by = (int)floorf(sy), bx = (int)floorf(sx);
        bool oob = ((unsigned)by > 13u) | ((unsigned)bx > 13u);
        oobmask |= oob ? (1u << k2) : 0u;
    }

    float4x acc[4];
#pragma unroll
    for (int nt = 0; nt < 4; ++nt) acc[nt] = (float4x){0.f, 0.f, 0.f, 0.f};

#pragma unroll
    for (int k2 = 0; k2 < 9; ++k2) {
        const int kh = k2 / 3, kw = k2 - kh * 3;
        float sy = (float)(plh + 2 + kh) + offr[k2].x;
        float sx = (float)(plw + 2 + kw) + offr[k2].y;
        float yf = floorf(sy), xf = floorf(sx);
        int by = (int)yf, bx = (int)xf;
        float wy1 = sy - yf, wx1 = sx - xf;
        float wy0 = 1.f - wy1, wx0 = 1.f - wx1;
        float w00 = wy0 * wx0, w01 = wy0 * wx1;
        float w10 = wy1 * wx0, w11 = wy1 * wx1;
        int byc = min(max(by, 0), 13), bxc = min(max(bx, 0), 13);
        int cb = (byc * 15 + bxc) * 72 + (lq << 3) + (half << 5);

        int kk = k2 * 2 + half;
        short8x c00 = *(const short8x*)&tile[cb];
        short8x c01 = *(const short8x*)&tile[cb + 72];
        short8x c10 = *(const short8x*)&tile[cb + 72 * 15];
        short8x c11 = *(const short8x*)&tile[cb + 72 * 16];
        float s[8];
#pragma unroll
        for (int j = 0; j < 8; ++j) {
            s[j] = w00 * bf2f((ushort)c00[j]) + w01 * bf2f((ushort)c01[j])
                 + w10 * bf2f((ushort)c10[j]) + w11 * bf2f((ushort)c11[j]);
        }
        union { short8x v; ushort u[8]; } A;
#pragma unroll
        for (int j = 0; j < 8; ++j) A.u[j] = f2bf(s[j]);
#pragma unroll
        for (int nt = 0; nt < 4; ++nt) {
            short8x bw = *(const short8x*)&Bd[(kk * 4 + nt) * 512 + (lane << 3)];
            acc[nt] = __builtin_amdgcn_mfma_f32_16x16x32_bf16(A.v, bw, acc[nt], 0, 0, 0);
        }
    }

    if (__any(oobmask != 0)) {
#pragma unroll 1
        for (int k2 = 0; k2 < 9; ++k2) {
            if (!__any((oobmask >> k2) & 1)) continue;
            bool oob = (oobmask >> k2) & 1;
            const int kh = k2 / 3, kw = k2 - kh * 3;
            float2 od = *(const float2*)&offl[p1 * 18 + k2 * 2];
            float sy = (float)(plh + 2 + kh) + od.x;
            float sx = (float)(plw + 2 + kw) + od.y;
            float yf = floorf(sy), xf = floorf(sx);
            int by = (int)yf, bx = (int)xf;
            float wy1 = sy - yf, wx1 = sx - xf;
            float wy0 = 1.f - wy1, wx0 = 1.f - wx1;
            float w00 = wy0 * wx0, w01 = wy0 * wx1;
            float w10 = wy1 * wx0, w11 = wy1 * wx1;
            int byc = min(max(by, 0), 13), bxc = min(max(bx, 0), 13);
            int cb = (byc * 15 + bxc) * 72 + (lq << 3) + (half << 5);
            int y0g = by + h0 - 3, x0g = bx + w0 - 3;
            int y1g = y0g + 1, x1g = x0g + 1;
            float m00 = ((unsigned)y0g < 128u && (unsigned)x0g < 128u) ? w00 : 0.f;
            float m01 = ((unsigned)y0g < 128u && (unsigned)x1g < 128u) ? w01 : 0.f;
            float m10 = ((unsigned)y1g < 128u && (unsigned)x0g < 128u) ? w10 : 0.f;
            float m11 = ((unsigned)y1g < 128u && (unsigned)x1g < 128u) ? w11 : 0.f;
            int y0c = min(max(y0g, 0), 127), y1c = min(max(y1g, 0), 127);
            int x0c = min(max(x0g, 0), 127), x1c = min(max(x1g, 0), 127);
            int i00 = (y0c << 7) + x0c, i01 = (y0c << 7) + x1c;
            int i10 = (y1c << 7) + x0c, i11 = (y1c << 7) + x1c;
            int kk = k2 * 2 + half;
            int cin0 = (half << 5) + (lq << 3);
            short8x c00 = *(const short8x*)&tile[cb];
            short8x c01 = *(const short8x*)&tile[cb + 72];
            short8x c10 = *(const short8x*)&tile[cb + 72 * 15];
            short8x c11 = *(const short8x*)&tile[cb + 72 * 16];
            float d[8];
#pragma unroll
            for (int j = 0; j < 8; ++j) {
                float sl = w00 * bf2f((ushort)c00[j]) + w01 * bf2f((ushort)c01[j])
                         + w10 * bf2f((ushort)c10[j]) + w11 * bf2f((ushort)c11[j]);
                const float* xp = xb + ((long)(cin0 + j) << 14);
                float sg = m00 * xp[i00] + m01 * xp[i01]
                         + m10 * xp[i10] + m11 * xp[i11];
                d[j] = oob ? (sg - sl) : 0.f;
            }
            union { short8x v; ushort u[8]; } A;
#pragma unroll
            for (int j = 0; j < 8; ++j) A.u[j] = f2bf(d[j]);
#pragma unroll
            for (int nt = 0; nt < 4; ++nt) {
                short8x bw = *(const short8x*)&Bd[(kk * 4 + nt) * 512 + (lane << 3)];
                acc[nt] = __builtin_amdgcn_mfma_f32_16x16x32_bf16(A.v, bw, acc[nt], 0, 0, 0);
            }
        }
    }

    __syncthreads();
    float* red = (float*)smem;
    if (half == 1) {
#pragma unroll
        for (int nt = 0; nt < 4; ++nt)
#pragma unroll
            for (int r = 0; r < 4; ++r) {
                int p = (wq << 4) + (lq << 2) + r;
                red[p * 65 + (nt << 4) + l15] = acc[nt][r];
            }
    }
    __syncthreads();
    if (half == 0) {
#pragma unroll
        for (int nt = 0; nt < 4; ++nt)
#pragma unroll
            for (int r = 0; r < 4; ++r) {
                int p = (wq << 4) + (lq << 2) + r;
                red[p * 65 + (nt << 4) + l15] += acc[nt][r];
            }
    }
    __syncthreads();

    {
        int n = tid >> 3, q = tid & 7;
        float bd = bdef[n];
        float* dst = out + (((long)(b * 64 + n)) << 14) + ((h0 + q) << 7) + w0;
        float v[8];
#pragma unroll
        for (int c = 0; c < 8; ++c) v[c] = red[(q * 8 + c) * 65 + n] + bd;
        float4x s0 = {v[0], v[1], v[2], v[3]};
        float4x s1 = {v[4], v[5], v[6], v[7]};
        *(float4x*)(dst) = s0;
        *(float4x*)(dst + 4) = s1;
    }
}

// ---------------------------------------------------------------------------
extern "C" void kernel_launch(void* const* d_in, const int* in_sizes, int n_in,
                              void* d_out, int out_size, void* d_ws, size_t ws_size,
                              hipStream_t stream) {
    const float* x     = (const float*)d_in[0];  // (4,64,128,128)
    const float* w_off = (const float*)d_in[1];  // (18,64,3,3)
    const float* b_off = (const float*)d_in[2];  // (18,)
    const float* w_def = (const float*)d_in[3];  // (64,64,3,3)
    const float* b_def = (const float*)d_in[4];  // (64,)
    float* out = (float*)d_out;                  // (4,64,128,128)

    const size_t NEED = 8388608ull + 73728ull + 36864ull + 16ull;
    const int DYN_LDS = 70144;

    static int lds_ok = -1;   // -1 unknown, 1 ok, 0 failed
    if (lds_ok == -1) {
        hipError_t e = hipFuncSetAttribute(
            (const void*)dcn_fused,
            hipFuncAttributeMaxDynamicSharedMemorySize, DYN_LDS);
        lds_ok = (e == hipSuccess) ? 1 : 0;
    }

    if (ws_size >= NEED && lds_ok == 1) {
        // fast path: xbf 8 MiB | Bd 73728 B | Bo 36864 B | zero page 16 B
        ushort* xbf = (ushort*)d_ws;                          // 4*16384*64 bf16
        ushort* Bd  = (ushort*)((char*)d_ws + 8388608);       // 36864 bf16
        ushort* Bo  = Bd + 36864;                             // 18432 bf16
        uint*   zp  = (uint*)((char*)d_ws + 8388608 + 73728 + 36864);
        hipLaunchKernelGGL(pack_all, dim3(944), dim3(128), 0, stream,
                           x, w_def, w_off, xbf, Bd, Bo, zp);
        hipLaunchKernelGGL(dcn_fused, dim3(512), dim3(512), DYN_LDS, stream,
                           x, xbf, Bd, Bo, b_off, b_def, (const ushort*)zp, out);
    } else {
        // fallback: verbatim R12 (proven)
        ushort* Bd = (ushort*)d_ws;                  // 36864 bf16 = 73728 B
        ushort* Bo = Bd + 36864;                     // 18432 bf16 = 36864 B
        hipLaunchKernelGGL(pack_weights, dim3(216), dim3(256), 0, stream,
                           w_def, w_off, Bd, Bo);
        hipLaunchKernelGGL(dcn_fused_fb, dim3(1024), dim3(512), 0, stream,
                           x, Bd, Bo, b_off, b_def, out);
    }
}

// Round 5
// 169.207 us; speedup vs baseline: 1.6427x; 1.6427x over previous
//
#include <hip/hip_runtime.h>

// B=4, CIN=COUT=64, H=W=128, 3x3 deformable conv, fp32 in/out.
// R17 = R16 resubmitted verbatim (container failed twice on R16; R13's
// identical-code precedent ran fine in R14, so infra flakiness is the
// dominant hypothesis; resubmitting unchanged disambiguates).
// R16 = R15 with the spill fixed: fast-path launch bounds (512,4) -> (512,2).
// R15 post-mortem: FETCH 267MB / WRITE 286MB symmetric excess = ~1KB/thread
// scratch spill. (512,4) empirically caps VGPR at 64 (R12 ladder); the
// 2-tile loop needs >64. LDS (70KB) caps residency at 2 blocks/CU anyway,
// so (512,2) (higher VGPR cap) keeps the same occupancy and removes the spill.

typedef __attribute__((ext_vector_type(8))) short short8x;
typedef __attribute__((ext_vector_type(4))) float float4x;
typedef unsigned short ushort;
typedef unsigned int uint;

__device__ __forceinline__ ushort f2bf(float f) {
    uint b = __float_as_uint(f);
    b += 0x7fffu + ((b >> 16) & 1u);
    return (ushort)(b >> 16);
}
__device__ __forceinline__ float bf2f(ushort u) {
    return __uint_as_float(((uint)u) << 16);
}

__device__ __forceinline__ void gload16(const void* g, void* l) {
    __builtin_amdgcn_global_load_lds(
        (const __attribute__((address_space(1))) void*)g,
        (__attribute__((address_space(3))) void*)l, 16, 0, 0);
}

// ===========================================================================
// FAST PATH (requires ws_size >= 8.5 MB and >64KB dynamic LDS support)
// ===========================================================================

__global__ __launch_bounds__(128) void pack_all(
    const float* __restrict__ x, const float* __restrict__ w_def,
    const float* __restrict__ w_off, ushort* __restrict__ xbf,
    ushort* __restrict__ Bd, ushort* __restrict__ Bo, uint* __restrict__ zp) {
    int tid = threadIdx.x, bid = blockIdx.x;
    if (bid < 512) {
        int p = (bid << 7) + tid;          // 0..65535 pixel id
        if (p == 0) { zp[0] = 0; zp[1] = 0; zp[2] = 0; zp[3] = 0; }
        int b = p >> 14;
        const float* src = x + ((long)b << 20) + (p & 16383);
        ushort* dst = xbf + ((long)p << 6);
        float v[64];
#pragma unroll
        for (int c = 0; c < 64; ++c) v[c] = src[(long)c << 14];
#pragma unroll
        for (int g = 0; g < 8; ++g) {
            uint4 d;
            d.x = (uint)f2bf(v[g * 8 + 0]) | ((uint)f2bf(v[g * 8 + 1]) << 16);
            d.y = (uint)f2bf(v[g * 8 + 2]) | ((uint)f2bf(v[g * 8 + 3]) << 16);
            d.z = (uint)f2bf(v[g * 8 + 4]) | ((uint)f2bf(v[g * 8 + 5]) << 16);
            d.w = (uint)f2bf(v[g * 8 + 6]) | ((uint)f2bf(v[g * 8 + 7]) << 16);
            *(uint4*)(dst + (g << 3)) = d;
        }
    } else {
        int idx = ((bid - 512) << 7) + tid;   // 0..55295
        if (idx < 36864) {
            int i = idx & 7;
            int lane = (idx >> 3) & 63;
            int nt = (idx >> 9) & 3;
            int kk = idx >> 11;
            int n = (nt << 4) + (lane & 15);
            int k2 = kk >> 1;
            int cin = ((kk & 1) << 5) + ((lane >> 4) << 3) + i;
            Bd[idx] = f2bf(w_def[(n * 64 + cin) * 9 + k2]);
        } else {
            int d = idx - 36864;
            int i = d & 7;
            int lane = (d >> 3) & 63;
            int nt = (d >> 9) & 1;
            int kk = d >> 10;
            int n = (nt << 4) + (lane & 15);
            int k2 = kk >> 1;
            int cin = ((kk & 1) << 5) + ((lane >> 4) << 3) + i;
            Bo[d] = (n < 18) ? f2bf(w_off[(n * 64 + cin) * 9 + k2]) : (ushort)0;
        }
    }
}

// ---------------------------------------------------------------------------
// Fused kernel (fast path). 512 blocks x 512 threads; block = 2 tiles of
// 8x8 pixels, double-buffered. wq = wv&3 owns pixels 16wq..16wq+15;
// half = wv>>2 owns cins 32half..+31 (and n-group half in stage 1).
// Dynamic LDS 70144 B: buf0 [0,32768) | buf1 [32768,65536) | offl 4608 B.
// red[64][65] (16640 B) overlays the CURRENT tile's buffer in the epilogue.
// __launch_bounds__(512,2): higher VGPR cap; LDS caps residency at 2/CU.
// ---------------------------------------------------------------------------
__global__ __launch_bounds__(512, 2) void dcn_fused(
    const float* __restrict__ x, const ushort* __restrict__ xbf,
    const ushort* __restrict__ Bd, const ushort* __restrict__ Bo,
    const float* __restrict__ boff, const float* __restrict__ bdef,
    const ushort* __restrict__ zp, float* __restrict__ out) {

    extern __shared__ __align__(16) char smem[];
    float* offl = (float*)(smem + 65536);      // [px 64][ch 18]

    int tid = threadIdx.x;
    int lane = tid & 63, wv = tid >> 6;
    int wq = wv & 3, half = wv >> 2;
    // XCD-aware swizzle: 512 blocks % 8 == 0 -> bijective.
    int raw = blockIdx.x;
    int blk = ((raw & 7) << 6) + (raw >> 3);
    int tile0 = blk << 1;                      // tiles {tile0, tile0+1}

    const ushort* xb2base = xbf;

    // ---- staging helper: 32 chunks x 1 KiB via global_load_lds dwordx4.
    auto stage_tile = [&](int tile_i, char* dst) {
        int tb = tile_i >> 8, tq = tile_i & 255;
        int th0 = (tq >> 4) << 3, tw0 = (tq & 15) << 3;
        const ushort* xb2 = xb2base + ((long)tb << 20);
#pragma unroll
        for (int c = 0; c < 4; ++c) {
            int chunk = wv + (c << 3);
            int o4 = (chunk << 6) + lane;           // byte/16, 0..2047
            int pos = (o4 * 7282) >> 16;            // /9 (exact)
            int slot = o4 - pos * 9;
            int ty = (pos * 4370) >> 16;            // /15 (exact)
            int tx = pos - ty * 15;
            int y = th0 - 3 + ty, xx = tw0 - 3 + tx;
            bool valid = ((unsigned)y < 128u) & ((unsigned)xx < 128u)
                       & (slot < 8) & (pos < 225);
            const ushort* gp = valid
                ? xb2 + (((y << 7) + xx) << 6) + (slot << 3)
                : zp;
            gload16(gp, dst + (chunk << 10));
        }
    };

    int l15 = lane & 15, lq = lane >> 4;
    int p1 = (wq << 4) + l15;          // this lane's A-row pixel
    int plh = p1 >> 3, plw = p1 & 7;

    // ---- prologue: stage tile0 into buf0, wait.
    stage_tile(tile0, smem);
    __syncthreads();

    for (int tt = 0; tt < 2; ++tt) {
        char* bufc = smem + (tt << 15);
        ushort* tile = (ushort*)bufc;          // [pos(225) stride 72][cin 64]
        int ti = tile0 + tt;
        int b = ti >> 8, t = ti & 255;
        int h0 = (t >> 4) << 3, w0 = (t & 15) << 3;
        const float* xb = x + ((long)b << 20);

        // ---- prefetch next tile into buf1 (async; latency hides under
        // stage-1; drained by the post-stage-1 barrier's vmcnt(0)).
        if (tt == 0) stage_tile(tile0 + 1, smem + 32768);

        // ---- stage 1: offset conv via MFMA, N-split.
        float4x oacc = {0.f, 0.f, 0.f, 0.f};
#pragma unroll
        for (int k2 = 0; k2 < 9; ++k2) {
            int kh = k2 / 3, kw = k2 - kh * 3;
            int pos = (plh + 2 + kh) * 15 + (plw + 2 + kw);
            int abase = pos * 72 + (lq << 3);
#pragma unroll
            for (int hf = 0; hf < 2; ++hf) {
                int kk = k2 * 2 + hf;
                short8x a = *(const short8x*)&tile[abase + hf * 32];
                short8x bo = *(const short8x*)&Bo[(kk * 2 + half) * 512 + (lane << 3)];
                oacc = __builtin_amdgcn_mfma_f32_16x16x32_bf16(a, bo, oacc, 0, 0, 0);
            }
        }
        {   // scatter D (col n = 16*half + l15, row = lq*4+r) + bias -> offl
            int n = (half << 4) + l15;
            if (n < 18) {
                float bo = boff[n];
#pragma unroll
                for (int r = 0; r < 4; ++r) {
                    int p = (wq << 4) + (lq << 2) + r;
                    offl[p * 18 + n] = oacc[r] + bo;
                }
            }
        }
        __syncthreads();

        // ---- offsets to registers (constant-indexed only) + oob mask
        float2 offr[9];
        uint oobmask = 0;
#pragma unroll
        for (int k2 = 0; k2 < 9; ++k2) {
            offr[k2] = *(const float2*)&offl[p1 * 18 + k2 * 2];
            const int kh = k2 / 3, kw = k2 - kh * 3;
            float sy = (float)(plh + 2 + kh) + offr[k2].x;
            float sx = (float)(plw + 2 + kw) + offr[k2].y;
            int by = (int)floorf(sy), bx = (int)floorf(sx);
            bool oob = ((unsigned)by > 13u) | ((unsigned)bx > 13u);
            oobmask |= oob ? (1u << k2) : 0u;
        }

        // ---- stage 2: 9 steps over this wave's cin-half
        float4x acc[4];
#pragma unroll
        for (int nt = 0; nt < 4; ++nt) acc[nt] = (float4x){0.f, 0.f, 0.f, 0.f};

#pragma unroll
        for (int k2 = 0; k2 < 9; ++k2) {
            const int kh = k2 / 3, kw = k2 - kh * 3;
            float sy = (float)(plh + 2 + kh) + offr[k2].x;
            float sx = (float)(plw + 2 + kw) + offr[k2].y;
            float yf = floorf(sy), xf = floorf(sx);
            int by = (int)yf, bx = (int)xf;
            float wy1 = sy - yf, wx1 = sx - xf;
            float wy0 = 1.f - wy1, wx0 = 1.f - wx1;
            float w00 = wy0 * wx0, w01 = wy0 * wx1;
            float w10 = wy1 * wx0, w11 = wy1 * wx1;
            int byc = min(max(by, 0), 13), bxc = min(max(bx, 0), 13);
            int cb = (byc * 15 + bxc) * 72 + (lq << 3) + (half << 5);

            int kk = k2 * 2 + half;
            short8x c00 = *(const short8x*)&tile[cb];
            short8x c01 = *(const short8x*)&tile[cb + 72];
            short8x c10 = *(const short8x*)&tile[cb + 72 * 15];
            short8x c11 = *(const short8x*)&tile[cb + 72 * 16];
            float s[8];
#pragma unroll
            for (int j = 0; j < 8; ++j) {
                s[j] = w00 * bf2f((ushort)c00[j]) + w01 * bf2f((ushort)c01[j])
                     + w10 * bf2f((ushort)c10[j]) + w11 * bf2f((ushort)c11[j]);
            }
            union { short8x v; ushort u[8]; } A;
#pragma unroll
            for (int j = 0; j < 8; ++j) A.u[j] = f2bf(s[j]);
#pragma unroll
            for (int nt = 0; nt < 4; ++nt) {
                short8x bw = *(const short8x*)&Bd[(kk * 4 + nt) * 512 + (lane << 3)];
                acc[nt] = __builtin_amdgcn_mfma_f32_16x16x32_bf16(A.v, bw, acc[nt], 0, 0, 0);
            }
        }

        // ---- cold exactness pass (own half): out-of-tile samples (~8 sigma,
        // never taken on this data).
        if (__any(oobmask != 0)) {
#pragma unroll 1
            for (int k2 = 0; k2 < 9; ++k2) {
                if (!__any((oobmask >> k2) & 1)) continue;
                bool oob = (oobmask >> k2) & 1;
                const int kh = k2 / 3, kw = k2 - kh * 3;
                float2 od = *(const float2*)&offl[p1 * 18 + k2 * 2];
                float sy = (float)(plh + 2 + kh) + od.x;
                float sx = (float)(plw + 2 + kw) + od.y;
                float yf = floorf(sy), xf = floorf(sx);
                int by = (int)yf, bx = (int)xf;
                float wy1 = sy - yf, wx1 = sx - xf;
                float wy0 = 1.f - wy1, wx0 = 1.f - wx1;
                float w00 = wy0 * wx0, w01 = wy0 * wx1;
                float w10 = wy1 * wx0, w11 = wy1 * wx1;
                int byc = min(max(by, 0), 13), bxc = min(max(bx, 0), 13);
                int cb = (byc * 15 + bxc) * 72 + (lq << 3) + (half << 5);
                int y0g = by + h0 - 3, x0g = bx + w0 - 3;
                int y1g = y0g + 1, x1g = x0g + 1;
                float m00 = ((unsigned)y0g < 128u && (unsigned)x0g < 128u) ? w00 : 0.f;
                float m01 = ((unsigned)y0g < 128u && (unsigned)x1g < 128u) ? w01 : 0.f;
                float m10 = ((unsigned)y1g < 128u && (unsigned)x0g < 128u) ? w10 : 0.f;
                float m11 = ((unsigned)y1g < 128u && (unsigned)x1g < 128u) ? w11 : 0.f;
                int y0c = min(max(y0g, 0), 127), y1c = min(max(y1g, 0), 127);
                int x0c = min(max(x0g, 0), 127), x1c = min(max(x1g, 0), 127);
                int i00 = (y0c << 7) + x0c, i01 = (y0c << 7) + x1c;
                int i10 = (y1c << 7) + x0c, i11 = (y1c << 7) + x1c;
                int kk = k2 * 2 + half;
                int cin0 = (half << 5) + (lq << 3);
                short8x c00 = *(const short8x*)&tile[cb];
                short8x c01 = *(const short8x*)&tile[cb + 72];
                short8x c10 = *(const short8x*)&tile[cb + 72 * 15];
                short8x c11 = *(const short8x*)&tile[cb + 72 * 16];
                float d[8];
#pragma unroll
                for (int j = 0; j < 8; ++j) {
                    float sl = w00 * bf2f((ushort)c00[j]) + w01 * bf2f((ushort)c01[j])
                             + w10 * bf2f((ushort)c10[j]) + w11 * bf2f((ushort)c11[j]);
                    const float* xp = xb + ((long)(cin0 + j) << 14);
                    float sg = m00 * xp[i00] + m01 * xp[i01]
                             + m10 * xp[i10] + m11 * xp[i11];
                    d[j] = oob ? (sg - sl) : 0.f;
                }
                union { short8x v; ushort u[8]; } A;
#pragma unroll
                for (int j = 0; j < 8; ++j) A.u[j] = f2bf(d[j]);
#pragma unroll
                for (int nt = 0; nt < 4; ++nt) {
                    short8x bw = *(const short8x*)&Bd[(kk * 4 + nt) * 512 + (lane << 3)];
                    acc[nt] = __builtin_amdgcn_mfma_f32_16x16x32_bf16(A.v, bw, acc[nt], 0, 0, 0);
                }
            }
        }

        // ---- reduce half pairs through LDS red[64][65] overlaying the
        // CURRENT buffer (dead after stage-2; next tile lives in the other).
        __syncthreads();
        float* red = (float*)bufc;
        if (half == 1) {
#pragma unroll
            for (int nt = 0; nt < 4; ++nt)
#pragma unroll
                for (int r = 0; r < 4; ++r) {
                    int p = (wq << 4) + (lq << 2) + r;
                    red[p * 65 + (nt << 4) + l15] = acc[nt][r];
                }
        }
        __syncthreads();
        if (half == 0) {
#pragma unroll
            for (int nt = 0; nt < 4; ++nt)
#pragma unroll
                for (int r = 0; r < 4; ++r) {
                    int p = (wq << 4) + (lq << 2) + r;
                    red[p * 65 + (nt << 4) + l15] += acc[nt][r];
                }
        }
        __syncthreads();

        // ---- store: 512 threads, thread = (cout n, row q); 2x float4
        {
            int n = tid >> 3, q = tid & 7;
            float bd = bdef[n];
            float* dst = out + (((long)(b * 64 + n)) << 14) + ((h0 + q) << 7) + w0;
            float v[8];
#pragma unroll
            for (int c = 0; c < 8; ++c) v[c] = red[(q * 8 + c) * 65 + n] + bd;
            float4x s0 = {v[0], v[1], v[2], v[3]};
            float4x s1 = {v[4], v[5], v[6], v[7]};
            *(float4x*)(dst) = s0;
            *(float4x*)(dst + 4) = s1;
        }
    }
}

// ===========================================================================
// FALLBACK PATH (verbatim R12, harness-proven at 110.4 µs; needs ~111 KB ws)
// ===========================================================================

__global__ __launch_bounds__(256) void pack_weights(
    const float* __restrict__ w_def, const float* __restrict__ w_off,
    ushort* __restrict__ Bd, ushort* __restrict__ Bo) {
    int idx = blockIdx.x * 256 + threadIdx.x;
    if (idx < 36864) {
        int i = idx & 7;
        int lane = (idx >> 3) & 63;
        int nt = (idx >> 9) & 3;
        int kk = idx >> 11;
        int n = (nt << 4) + (lane & 15);
        int k2 = kk >> 1;
        int cin = ((kk & 1) << 5) + ((lane >> 4) << 3) + i;
        Bd[idx] = f2bf(w_def[(n * 64 + cin) * 9 + k2]);
    } else if (idx < 36864 + 18432) {
        int d = idx - 36864;
        int i = d & 7;
        int lane = (d >> 3) & 63;
        int nt = (d >> 9) & 1;
        int kk = d >> 10;
        int n = (nt << 4) + (lane & 15);
        int k2 = kk >> 1;
        int cin = ((kk & 1) << 5) + ((lane >> 4) << 3) + i;
        Bo[d] = (n < 18) ? f2bf(w_off[(n * 64 + cin) * 9 + k2]) : (ushort)0;
    }
}

__global__ __launch_bounds__(512, 4) void dcn_fused_fb(
    const float* __restrict__ x, const ushort* __restrict__ Bd,
    const ushort* __restrict__ Bo, const float* __restrict__ boff,
    const float* __restrict__ bdef, float* __restrict__ out) {

    int tid = threadIdx.x;
    int lane = tid & 63, wv = tid >> 6;
    int wq = wv & 3, half = wv >> 2;
    int blk = blockIdx.x;
    int b = blk >> 8, t = blk & 255;
    int h0 = (t >> 4) << 3, w0 = (t & 15) << 3;

    __shared__ __align__(16) char smem[37008];
    ushort* tile = (ushort*)smem;
    float* offl = (float*)(smem + 32400);

    const float* xb = x + ((long)b << 20);

    if (tid < 450) {
        int pos = tid >> 1, ch = (tid & 1) << 5;
        int ty = pos / 15, tx = pos - ty * 15;
        int y = h0 - 3 + ty, xx = w0 - 3 + tx;
        bool valid = ((unsigned)y < 128u) & ((unsigned)xx < 128u);
        int yc = min(max(y, 0), 127), xc = min(max(xx, 0), 127);
        const float* gp = xb + ((long)ch << 14) + (yc << 7) + xc;
        uint4* trow = (uint4*)&tile[pos * 72 + ch];
#pragma unroll
        for (int c8 = 0; c8 < 4; ++c8) {
            const float* g8 = gp + (c8 << 17);
            float v[8];
#pragma unroll
            for (int j = 0; j < 8; ++j) v[j] = valid ? g8[j << 14] : 0.f;
            uint4 d;
            d.x = (uint)f2bf(v[0]) | ((uint)f2bf(v[1]) << 16);
            d.y = (uint)f2bf(v[2]) | ((uint)f2bf(v[3]) << 16);
            d.z = (uint)f2bf(v[4]) | ((uint)f2bf(v[5]) << 16);
            d.w = (uint)f2bf(v[6]) | ((uint)f2bf(v[7]) << 16);
            trow[c8] = d;
        }
    }
    __syncthreads();

    int l15 = lane & 15, lq = lane >> 4;
    int p1 = (wq << 4) + l15;
    int plh = p1 >> 3, plw = p1 & 7;

    float4x oacc = {0.f, 0.f, 0.f, 0.f};
#pragma unroll
    for (int k2 = 0; k2 < 9; ++k2) {
        int kh = k2 / 3, kw = k2 - kh * 3;
        int pos = (plh + 2 + kh) * 15 + (plw + 2 + kw);
        int abase = pos * 72 + (lq << 3);
#pragma unroll
        for (int hf = 0; hf < 2; ++hf) {
            int kk = k2 * 2 + hf;
            short8x a = *(const short8x*)&tile[abase + hf * 32];
            short8x bo = *(const short8x*)&Bo[(kk * 2 + half) * 512 + (lane << 3)];
            oacc = __builtin_amdgcn_mfma_f32_16x16x32_bf16(a, bo, oacc, 0, 0, 0);
        }
    }
    {
        int n = (half << 4) + l15;
        if (n < 18) {
            float bo = boff[n];
#pragma unroll
            for (int r = 0; r < 4; ++r) {
                int p = (wq << 4) + (lq << 2) + r;
                offl[p * 18 + n] = oacc[r] + bo;
            }
        }
    }
    __syncthreads();

    float2 offr[9];
    uint oobmask = 0;
#pragma unroll
    for (int k2 = 0; k2 < 9; ++k2) {
        offr[k2] = *(const float2*)&offl[p1 * 18 + k2 * 2];
        const int kh = k2 / 3, kw = k2 - kh * 3;
        float sy = (float)(plh + 2 + kh) + offr[k2].x;
        float sx = (float)(plw + 2 + kw) + offr[k2].y;
        int by = (int)floorf(sy), bx = (int)floorf(sx);
        bool oob = ((unsigned)by > 13u) | ((unsigned)bx > 13u);
        oobmask |= oob ? (1u << k2) : 0u;
    }

    float4x acc[4];
#pragma unroll
    for (int nt = 0; nt < 4; ++nt) acc[nt] = (float4x){0.f, 0.f, 0.f, 0.f};

#pragma unroll
    for (int k2 = 0; k2 < 9; ++k2) {
        const int kh = k2 / 3, kw = k2 - kh * 3;
        float sy = (float)(plh + 2 + kh) + offr[k2].x;
        float sx = (float)(plw + 2 + kw) + offr[k2].y;
        float yf = floorf(sy), xf = floorf(sx);
        int by = (int)yf, bx = (int)xf;
        float wy1 = sy - yf, wx1 = sx - xf;
        float wy0 = 1.f - wy1, wx0 = 1.f - wx1;
        float w00 = wy0 * wx0, w01 = wy0 * wx1;
        float w10 = wy1 * wx0, w11 = wy1 * wx1;
        int byc = min(max(by, 0), 13), bxc = min(max(bx, 0), 13);
        int cb = (byc * 15 + bxc) * 72 + (lq << 3) + (half << 5);

        int kk = k2 * 2 + half;
        short8x c00 = *(const short8x*)&tile[cb];
        short8x c01 = *(const short8x*)&tile[cb + 72];
        short8x c10 = *(const short8x*)&tile[cb + 72 * 15];
        short8x c11 = *(const short8x*)&tile[cb + 72 * 16];
        float s[8];
#pragma unroll
        for (int j = 0; j < 8; ++j) {
            s[j] = w00 * bf2f((ushort)c00[j]) + w01 * bf2f((ushort)c01[j])
                 + w10 * bf2f((ushort)c10[j]) + w11 * bf2f((ushort)c11[j]);
        }
        union { short8x v; ushort u[8]; } A;
#pragma unroll
        for (int j = 0; j < 8; ++j) A.u[j] = f2bf(s[j]);
#pragma unroll
        for (int nt = 0; nt < 4; ++nt) {
            short8x bw = *(const short8x*)&Bd[(kk * 4 + nt) * 512 + (lane << 3)];
            acc[nt] = __builtin_amdgcn_mfma_f32_16x16x32_bf16(A.v, bw, acc[nt], 0, 0, 0);
        }
    }

    if (__any(oobmask != 0)) {
#pragma unroll 1
        for (int k2 = 0; k2 < 9; ++k2) {
            if (!__any((oobmask >> k2) & 1)) continue;
            bool oob = (oobmask >> k2) & 1;
            const int kh = k2 / 3, kw = k2 - kh * 3;
            float2 od = *(const float2*)&offl[p1 * 18 + k2 * 2];
            float sy = (float)(plh + 2 + kh) + od.x;
            float sx = (float)(plw + 2 + kw) + od.y;
            float yf = floorf(sy), xf = floorf(sx);
            int by = (int)yf, bx = (int)xf;
            float wy1 = sy - yf, wx1 = sx - xf;
            float wy0 = 1.f - wy1, wx0 = 1.f - wx1;
            float w00 = wy0 * wx0, w01 = wy0 * wx1;
            float w10 = wy1 * wx0, w11 = wy1 * wx1;
            int byc = min(max(by, 0), 13), bxc = min(max(bx, 0), 13);
            int cb = (byc * 15 + bxc) * 72 + (lq << 3) + (half << 5);
            int y0g = by + h0 - 3, x0g = bx + w0 - 3;
            int y1g = y0g + 1, x1g = x0g + 1;
            float m00 = ((unsigned)y0g < 128u && (unsigned)x0g < 128u) ? w00 : 0.f;
            float m01 = ((unsigned)y0g < 128u && (unsigned)x1g < 128u) ? w01 : 0.f;
            float m10 = ((unsigned)y1g < 128u && (unsigned)x0g < 128u) ? w10 : 0.f;
            float m11 = ((unsigned)y1g < 128u && (unsigned)x1g < 128u) ? w11 : 0.f;
            int y0c = min(max(y0g, 0), 127), y1c = min(max(y1g, 0), 127);
            int x0c = min(max(x0g, 0), 127), x1c = min(max(x1g, 0), 127);
            int i00 = (y0c << 7) + x0c, i01 = (y0c << 7) + x1c;
            int i10 = (y1c << 7) + x0c, i11 = (y1c << 7) + x1c;
            int kk = k2 * 2 + half;
            int cin0 = (half << 5) + (lq << 3);
            short8x c00 = *(const short8x*)&tile[cb];
            short8x c01 = *(const short8x*)&tile[cb + 72];
            short8x c10 = *(const short8x*)&tile[cb + 72 * 15];
            short8x c11 = *(const short8x*)&tile[cb + 72 * 16];
            float d[8];
#pragma unroll
            for (int j = 0; j < 8; ++j) {
                float sl = w00 * bf2f((ushort)c00[j]) + w01 * bf2f((ushort)c01[j])
                         + w10 * bf2f((ushort)c10[j]) + w11 * bf2f((ushort)c11[j]);
                const float* xp = xb + ((long)(cin0 + j) << 14);
                float sg = m00 * xp[i00] + m01 * xp[i01]
                         + m10 * xp[i10] + m11 * xp[i11];
                d[j] = oob ? (sg - sl) : 0.f;
            }
            union { short8x v; ushort u[8]; } A;
#pragma unroll
            for (int j = 0; j < 8; ++j) A.u[j] = f2bf(d[j]);
#pragma unroll
            for (int nt = 0; nt < 4; ++nt) {
                short8x bw = *(const short8x*)&Bd[(kk * 4 + nt) * 512 + (lane << 3)];
                acc[nt] = __builtin_amdgcn_mfma_f32_16x16x32_bf16(A.v, bw, acc[nt], 0, 0, 0);
            }
        }
    }

    __syncthreads();
    float* red = (float*)smem;
    if (half == 1) {
#pragma unroll
        for (int nt = 0; nt < 4; ++nt)
#pragma unroll
            for (int r = 0; r < 4; ++r) {
                int p = (wq << 4) + (lq << 2) + r;
                red[p * 65 + (nt << 4) + l15] = acc[nt][r];
            }
    }
    __syncthreads();
    if (half == 0) {
#pragma unroll
        for (int nt = 0; nt < 4; ++nt)
#pragma unroll
            for (int r = 0; r < 4; ++r) {
                int p = (wq << 4) + (lq << 2) + r;
                red[p * 65 + (nt << 4) + l15] += acc[nt][r];
            }
    }
    __syncthreads();

    {
        int n = tid >> 3, q = tid & 7;
        float bd = bdef[n];
        float* dst = out + (((long)(b * 64 + n)) << 14) + ((h0 + q) << 7) + w0;
        float v[8];
#pragma unroll
        for (int c = 0; c < 8; ++c) v[c] = red[(q * 8 + c) * 65 + n] + bd;
        float4x s0 = {v[0], v[1], v[2], v[3]};
        float4x s1 = {v[4], v[5], v[6], v[7]};
        *(float4x*)(dst) = s0;
        *(float4x*)(dst + 4) = s1;
    }
}

// ---------------------------------------------------------------------------
extern "C" void kernel_launch(void* const* d_in, const int* in_sizes, int n_in,
                              void* d_out, int out_size, void* d_ws, size_t ws_size,
                              hipStream_t stream) {
    const float* x     = (const float*)d_in[0];  // (4,64,128,128)
    const float* w_off = (const float*)d_in[1];  // (18,64,3,3)
    const float* b_off = (const float*)d_in[2];  // (18,)
    const float* w_def = (const float*)d_in[3];  // (64,64,3,3)
    const float* b_def = (const float*)d_in[4];  // (64,)
    float* out = (float*)d_out;                  // (4,64,128,128)

    const size_t NEED = 8388608ull + 73728ull + 36864ull + 16ull;
    const int DYN_LDS = 70144;

    static int lds_ok = -1;   // -1 unknown, 1 ok, 0 failed
    if (lds_ok == -1) {
        hipError_t e = hipFuncSetAttribute(
            (const void*)dcn_fused,
            hipFuncAttributeMaxDynamicSharedMemorySize, DYN_LDS);
        lds_ok = (e == hipSuccess) ? 1 : 0;
    }

    if (ws_size >= NEED && lds_ok == 1) {
        // fast path: xbf 8 MiB | Bd 73728 B | Bo 36864 B | zero page 16 B
        ushort* xbf = (ushort*)d_ws;                          // 4*16384*64 bf16
        ushort* Bd  = (ushort*)((char*)d_ws + 8388608);       // 36864 bf16
        ushort* Bo  = Bd + 36864;                             // 18432 bf16
        uint*   zp  = (uint*)((char*)d_ws + 8388608 + 73728 + 36864);
        hipLaunchKernelGGL(pack_all, dim3(944), dim3(128), 0, stream,
                           x, w_def, w_off, xbf, Bd, Bo, zp);
        hipLaunchKernelGGL(dcn_fused, dim3(512), dim3(512), DYN_LDS, stream,
                           x, xbf, Bd, Bo, b_off, b_def, (const ushort*)zp, out);
    } else {
        // fallback: verbatim R12 (proven)
        ushort* Bd = (ushort*)d_ws;                  // 36864 bf16 = 73728 B
        ushort* Bo = Bd + 36864;                     // 18432 bf16 = 36864 B
        hipLaunchKernelGGL(pack_weights, dim3(216), dim3(256), 0, stream,
                           w_def, w_off, Bd, Bo);
        hipLaunchKernelGGL(dcn_fused_fb, dim3(1024), dim3(512), 0, stream,
                           x, Bd, Bo, b_off, b_def, out);
    }
}

// Round 6
// 111.047 us; speedup vs baseline: 2.5030x; 1.5237x over previous
//
#include <hip/hip_runtime.h>

// B=4, CIN=COUT=64, H=W=128, 3x3 deformable conv, fp32 in/out.
// R18 = R14 single-tile structure + (512,2) launch bounds.
// R15-R17 post-mortem: the 2-tile double-buffer loop spills at every
// reachable VGPR cap (64: ~1KB/thread, 128: ~0.5KB/thread scratch traffic)
// -> abandoned. R17 DID validate the cap ladder: (512,N) -> 512/(2N) VGPRs
// (R17 measured 128 at (512,2)).
// R18 applies that knob to the proven single-tile body (fits 64, no spill):
// 128-cap = pure scheduling headroom for stage-1/2 B-fragment + ds_read
// hoisting. Trades residency 4->2 blocks/CU for ~2-3 iterations of load ILP.
//  - pack_all: x -> bf16 channel-last xbf (8 MB ws) + weight packing.
//  - dcn_fused: 1024 blocks x 1 tile, 32x global_load_lds dwordx4 staging,
//    static 37 KB LDS, XCD-aware swizzle.

typedef __attribute__((ext_vector_type(8))) short short8x;
typedef __attribute__((ext_vector_type(4))) float float4x;
typedef unsigned short ushort;
typedef unsigned int uint;

__device__ __forceinline__ ushort f2bf(float f) {
    uint b = __float_as_uint(f);
    b += 0x7fffu + ((b >> 16) & 1u);
    return (ushort)(b >> 16);
}
__device__ __forceinline__ float bf2f(ushort u) {
    return __uint_as_float(((uint)u) << 16);
}

__device__ __forceinline__ void gload16(const void* g, void* l) {
    __builtin_amdgcn_global_load_lds(
        (const __attribute__((address_space(1))) void*)g,
        (__attribute__((address_space(3))) void*)l, 16, 0, 0);
}

// ===========================================================================
// FAST PATH (requires ws_size >= 8.5 MB)
// ===========================================================================

__global__ __launch_bounds__(128) void pack_all(
    const float* __restrict__ x, const float* __restrict__ w_def,
    const float* __restrict__ w_off, ushort* __restrict__ xbf,
    ushort* __restrict__ Bd, ushort* __restrict__ Bo, uint* __restrict__ zp) {
    int tid = threadIdx.x, bid = blockIdx.x;
    if (bid < 512) {
        int p = (bid << 7) + tid;          // 0..65535 pixel id
        if (p == 0) { zp[0] = 0; zp[1] = 0; zp[2] = 0; zp[3] = 0; }
        int b = p >> 14;
        const float* src = x + ((long)b << 20) + (p & 16383);
        ushort* dst = xbf + ((long)p << 6);
        float v[64];
#pragma unroll
        for (int c = 0; c < 64; ++c) v[c] = src[(long)c << 14];
#pragma unroll
        for (int g = 0; g < 8; ++g) {
            uint4 d;
            d.x = (uint)f2bf(v[g * 8 + 0]) | ((uint)f2bf(v[g * 8 + 1]) << 16);
            d.y = (uint)f2bf(v[g * 8 + 2]) | ((uint)f2bf(v[g * 8 + 3]) << 16);
            d.z = (uint)f2bf(v[g * 8 + 4]) | ((uint)f2bf(v[g * 8 + 5]) << 16);
            d.w = (uint)f2bf(v[g * 8 + 6]) | ((uint)f2bf(v[g * 8 + 7]) << 16);
            *(uint4*)(dst + (g << 3)) = d;
        }
    } else {
        int idx = ((bid - 512) << 7) + tid;   // 0..55295
        if (idx < 36864) {
            int i = idx & 7;
            int lane = (idx >> 3) & 63;
            int nt = (idx >> 9) & 3;
            int kk = idx >> 11;
            int n = (nt << 4) + (lane & 15);
            int k2 = kk >> 1;
            int cin = ((kk & 1) << 5) + ((lane >> 4) << 3) + i;
            Bd[idx] = f2bf(w_def[(n * 64 + cin) * 9 + k2]);
        } else {
            int d = idx - 36864;
            int i = d & 7;
            int lane = (d >> 3) & 63;
            int nt = (d >> 9) & 1;
            int kk = d >> 10;
            int n = (nt << 4) + (lane & 15);
            int k2 = kk >> 1;
            int cin = ((kk & 1) << 5) + ((lane >> 4) << 3) + i;
            Bo[d] = (n < 18) ? f2bf(w_off[(n * 64 + cin) * 9 + k2]) : (ushort)0;
        }
    }
}

// ---------------------------------------------------------------------------
// Fused kernel (fast path). Block = 8x8 pixel tile, 512 threads = 8 waves.
// wq = wv&3 owns pixels 16wq..16wq+15; half = wv>>2 owns cins 32half..+31.
// __launch_bounds__(512,2): 128-VGPR cap (R17-measured). LDS 37 KB would
// allow 4 blocks/CU; VGPR occupancy gives 2 -> trades TLP for load ILP.
// ---------------------------------------------------------------------------
__global__ __launch_bounds__(512, 2) void dcn_fused(
    const float* __restrict__ x, const ushort* __restrict__ xbf,
    const ushort* __restrict__ Bd, const ushort* __restrict__ Bo,
    const float* __restrict__ boff, const float* __restrict__ bdef,
    const ushort* __restrict__ zp, float* __restrict__ out) {

    int tid = threadIdx.x;
    int lane = tid & 63, wv = tid >> 6;
    int wq = wv & 3, half = wv >> 2;
    // XCD-aware swizzle: 1024 blocks % 8 == 0 -> bijective.
    int raw = blockIdx.x;
    int blk = ((raw & 7) << 7) + (raw >> 3);
    int b = blk >> 8, t = blk & 255;
    int h0 = (t >> 4) << 3, w0 = (t & 15) << 3;

    // Manual shared layout (37008 B): tile 32400 B | offl 4608 B.
    // Staging writes 32 KiB linearly (chunk 31 spills 368 B into offl's
    // start; offl is fully rewritten by stage-1 before any read).
    // Epilogue reuses bytes 0..16640 as red[64][65] f32.
    __shared__ __align__(16) char smem[37008];
    ushort* tile = (ushort*)smem;              // [pos(225) stride 72][cin 64]
    float* offl = (float*)(smem + 32400);      // [px 64][ch 18]

    const float* xb = x + ((long)b << 20);

    // ---- stage halo: 32 chunks x 1 KiB via global_load_lds dwordx4.
    // LDS byte o = chunk*1024 + lane*16; pos = (o/16)/9, slot = (o/16)%9.
    // slot<8 -> cins 8*slot..8*slot+7 of pixel (h0-3+ty, w0-3+tx) from the
    // channel-last bf16 image; slot==8 (row pad) and OOB rows -> zero page.
    {
        const ushort* xb2 = xbf + ((long)b << 20);  // b*16384 pixels * 64 ch
#pragma unroll
        for (int c = 0; c < 4; ++c) {
            int chunk = wv + (c << 3);
            int o4 = (chunk << 6) + lane;           // byte/16, 0..2047
            int pos = (o4 * 7282) >> 16;            // /9 (exact, o4<=2047)
            int slot = o4 - pos * 9;
            int ty = (pos * 4370) >> 16;            // /15 (exact, pos<=227)
            int tx = pos - ty * 15;
            int y = h0 - 3 + ty, xx = w0 - 3 + tx;
            bool valid = ((unsigned)y < 128u) & ((unsigned)xx < 128u) & (slot < 8);
            const ushort* gp = valid
                ? xb2 + (((y << 7) + xx) << 6) + (slot << 3)
                : zp;
            gload16(gp, smem + (chunk << 10));
        }
    }
    __syncthreads();   // waits vmcnt(0) before barrier

    int l15 = lane & 15, lq = lane >> 4;
    int p1 = (wq << 4) + l15;          // this lane's A-row pixel
    int plh = p1 >> 3, plw = p1 & 7;

    // ---- stage 1: offset conv via MFMA, N-split.
    float4x oacc = {0.f, 0.f, 0.f, 0.f};
#pragma unroll
    for (int k2 = 0; k2 < 9; ++k2) {
        int kh = k2 / 3, kw = k2 - kh * 3;
        int pos = (plh + 2 + kh) * 15 + (plw + 2 + kw);
        int abase = pos * 72 + (lq << 3);
#pragma unroll
        for (int hf = 0; hf < 2; ++hf) {
            int kk = k2 * 2 + hf;
            short8x a = *(const short8x*)&tile[abase + hf * 32];
            short8x bo = *(const short8x*)&Bo[(kk * 2 + half) * 512 + (lane << 3)];
            oacc = __builtin_amdgcn_mfma_f32_16x16x32_bf16(a, bo, oacc, 0, 0, 0);
        }
    }
    {   // scatter D (col n = 16*half + l15, row = lq*4+r) + bias -> offl
        int n = (half << 4) + l15;
        if (n < 18) {
            float bo = boff[n];
#pragma unroll
            for (int r = 0; r < 4; ++r) {
                int p = (wq << 4) + (lq << 2) + r;
                offl[p * 18 + n] = oacc[r] + bo;
            }
        }
    }
    __syncthreads();

    // ---- offsets to registers (constant-indexed only) + oob mask
    float2 offr[9];
    uint oobmask = 0;
#pragma unroll
    for (int k2 = 0; k2 < 9; ++k2) {
        offr[k2] = *(const float2*)&offl[p1 * 18 + k2 * 2];
        const int kh = k2 / 3, kw = k2 - kh * 3;
        float sy = (float)(plh + 2 + kh) + offr[k2].x;
        float sx = (float)(plw + 2 + kw) + offr[k2].y;
        int by = (int)floorf(sy), bx = (int)floorf(sx);
        bool oob = ((unsigned)by > 13u) | ((unsigned)bx > 13u);
        oobmask |= oob ? (1u << k2) : 0u;
    }

    // ---- stage 2: 9 steps over this wave's cin-half
    float4x acc[4];
#pragma unroll
    for (int nt = 0; nt < 4; ++nt) acc[nt] = (float4x){0.f, 0.f, 0.f, 0.f};

#pragma unroll
    for (int k2 = 0; k2 < 9; ++k2) {
        const int kh = k2 / 3, kw = k2 - kh * 3;
        float sy = (float)(plh + 2 + kh) + offr[k2].x;
        float sx = (float)(plw + 2 + kw) + offr[k2].y;
        float yf = floorf(sy), xf = floorf(sx);
        int by = (int)yf, bx = (int)xf;
        float wy1 = sy - yf, wx1 = sx - xf;
        float wy0 = 1.f - wy1, wx0 = 1.f - wx1;
        float w00 = wy0 * wx0, w01 = wy0 * wx1;
        float w10 = wy1 * wx0, w11 = wy1 * wx1;
        int byc = min(max(by, 0), 13), bxc = min(max(bx, 0), 13);
        int cb = (byc * 15 + bxc) * 72 + (lq << 3) + (half << 5);

        int kk = k2 * 2 + half;
        short8x c00 = *(const short8x*)&tile[cb];
        short8x c01 = *(const short8x*)&tile[cb + 72];
        short8x c10 = *(const short8x*)&tile[cb + 72 * 15];
        short8x c11 = *(const short8x*)&tile[cb + 72 * 16];
        float s[8];
#pragma unroll
        for (int j = 0; j < 8; ++j) {
            s[j] = w00 * bf2f((ushort)c00[j]) + w01 * bf2f((ushort)c01[j])
                 + w10 * bf2f((ushort)c10[j]) + w11 * bf2f((ushort)c11[j]);
        }
        union { short8x v; ushort u[8]; } A;
#pragma unroll
        for (int j = 0; j < 8; ++j) A.u[j] = f2bf(s[j]);
#pragma unroll
        for (int nt = 0; nt < 4; ++nt) {
            short8x bw = *(const short8x*)&Bd[(kk * 4 + nt) * 512 + (lane << 3)];
            acc[nt] = __builtin_amdgcn_mfma_f32_16x16x32_bf16(A.v, bw, acc[nt], 0, 0, 0);
        }
    }

    // ---- cold exactness pass (own half): out-of-tile samples (~8 sigma,
    // never taken on this data).
    if (__any(oobmask != 0)) {
#pragma unroll 1
        for (int k2 = 0; k2 < 9; ++k2) {
            if (!__any((oobmask >> k2) & 1)) continue;
            bool oob = (oobmask >> k2) & 1;
            const int kh = k2 / 3, kw = k2 - kh * 3;
            float2 od = *(const float2*)&offl[p1 * 18 + k2 * 2];
            float sy = (float)(plh + 2 + kh) + od.x;
            float sx = (float)(plw + 2 + kw) + od.y;
            float yf = floorf(sy), xf = floorf(sx);
            int by = (int)yf, bx = (int)xf;
            float wy1 = sy - yf, wx1 = sx - xf;
            float wy0 = 1.f - wy1, wx0 = 1.f - wx1;
            float w00 = wy0 * wx0, w01 = wy0 * wx1;
            float w10 = wy1 * wx0, w11 = wy1 * wx1;
            int byc = min(max(by, 0), 13), bxc = min(max(bx, 0), 13);
            int cb = (byc * 15 + bxc) * 72 + (lq << 3) + (half << 5);
            int y0g = by + h0 - 3, x0g = bx + w0 - 3;
            int y1g = y0g + 1, x1g = x0g + 1;
            float m00 = ((unsigned)y0g < 128u && (unsigned)x0g < 128u) ? w00 : 0.f;
            float m01 = ((unsigned)y0g < 128u && (unsigned)x1g < 128u) ? w01 : 0.f;
            float m10 = ((unsigned)y1g < 128u && (unsigned)x0g < 128u) ? w10 : 0.f;
            float m11 = ((unsigned)y1g < 128u && (unsigned)x1g < 128u) ? w11 : 0.f;
            int y0c = min(max(y0g, 0), 127), y1c = min(max(y1g, 0), 127);
            int x0c = min(max(x0g, 0), 127), x1c = min(max(x1g, 0), 127);
            int i00 = (y0c << 7) + x0c, i01 = (y0c << 7) + x1c;
            int i10 = (y1c << 7) + x0c, i11 = (y1c << 7) + x1c;
            int kk = k2 * 2 + half;
            int cin0 = (half << 5) + (lq << 3);
            short8x c00 = *(const short8x*)&tile[cb];
            short8x c01 = *(const short8x*)&tile[cb + 72];
            short8x c10 = *(const short8x*)&tile[cb + 72 * 15];
            short8x c11 = *(const short8x*)&tile[cb + 72 * 16];
            float d[8];
#pragma unroll
            for (int j = 0; j < 8; ++j) {
                float sl = w00 * bf2f((ushort)c00[j]) + w01 * bf2f((ushort)c01[j])
                         + w10 * bf2f((ushort)c10[j]) + w11 * bf2f((ushort)c11[j]);
                const float* xp = xb + ((long)(cin0 + j) << 14);
                float sg = m00 * xp[i00] + m01 * xp[i01]
                         + m10 * xp[i10] + m11 * xp[i11];
                d[j] = oob ? (sg - sl) : 0.f;
            }
            union { short8x v; ushort u[8]; } A;
#pragma unroll
            for (int j = 0; j < 8; ++j) A.u[j] = f2bf(d[j]);
#pragma unroll
            for (int nt = 0; nt < 4; ++nt) {
                short8x bw = *(const short8x*)&Bd[(kk * 4 + nt) * 512 + (lane << 3)];
                acc[nt] = __builtin_amdgcn_mfma_f32_16x16x32_bf16(A.v, bw, acc[nt], 0, 0, 0);
            }
        }
    }

    // ---- reduce half pairs through LDS red[64][65]
    __syncthreads();
    float* red = (float*)smem;   // 64*65*4 = 16640 B over tile
    if (half == 1) {
#pragma unroll
        for (int nt = 0; nt < 4; ++nt)
#pragma unroll
            for (int r = 0; r < 4; ++r) {
                int p = (wq << 4) + (lq << 2) + r;
                red[p * 65 + (nt << 4) + l15] = acc[nt][r];
            }
    }
    __syncthreads();
    if (half == 0) {
#pragma unroll
        for (int nt = 0; nt < 4; ++nt)
#pragma unroll
            for (int r = 0; r < 4; ++r) {
                int p = (wq << 4) + (lq << 2) + r;
                red[p * 65 + (nt << 4) + l15] += acc[nt][r];
            }
    }
    __syncthreads();

    // ---- store: 512 threads, thread = (cout n, row q); 2x float4 per thread
    {
        int n = tid >> 3, q = tid & 7;
        float bd = bdef[n];
        float* dst = out + (((long)(b * 64 + n)) << 14) + ((h0 + q) << 7) + w0;
        float v[8];
#pragma unroll
        for (int c = 0; c < 8; ++c) v[c] = red[(q * 8 + c) * 65 + n] + bd;
        float4x s0 = {v[0], v[1], v[2], v[3]};
        float4x s1 = {v[4], v[5], v[6], v[7]};
        *(float4x*)(dst) = s0;
        *(float4x*)(dst + 4) = s1;
    }
}

// ===========================================================================
// FALLBACK PATH (verbatim R12, harness-proven at 110.4 µs; needs ~111 KB ws)
// ===========================================================================

__global__ __launch_bounds__(256) void pack_weights(
    const float* __restrict__ w_def, const float* __restrict__ w_off,
    ushort* __restrict__ Bd, ushort* __restrict__ Bo) {
    int idx = blockIdx.x * 256 + threadIdx.x;
    if (idx < 36864) {
        int i = idx & 7;
        int lane = (idx >> 3) & 63;
        int nt = (idx >> 9) & 3;
        int kk = idx >> 11;
        int n = (nt << 4) + (lane & 15);
        int k2 = kk >> 1;
        int cin = ((kk & 1) << 5) + ((lane >> 4) << 3) + i;
        Bd[idx] = f2bf(w_def[(n * 64 + cin) * 9 + k2]);
    } else if (idx < 36864 + 18432) {
        int d = idx - 36864;
        int i = d & 7;
        int lane = (d >> 3) & 63;
        int nt = (d >> 9) & 1;
        int kk = d >> 10;
        int n = (nt << 4) + (lane & 15);
        int k2 = kk >> 1;
        int cin = ((kk & 1) << 5) + ((lane >> 4) << 3) + i;
        Bo[d] = (n < 18) ? f2bf(w_off[(n * 64 + cin) * 9 + k2]) : (ushort)0;
    }
}

__global__ __launch_bounds__(512, 4) void dcn_fused_fb(
    const float* __restrict__ x, const ushort* __restrict__ Bd,
    const ushort* __restrict__ Bo, const float* __restrict__ boff,
    const float* __restrict__ bdef, float* __restrict__ out) {

    int tid = threadIdx.x;
    int lane = tid & 63, wv = tid >> 6;
    int wq = wv & 3, half = wv >> 2;
    int blk = blockIdx.x;
    int b = blk >> 8, t = blk & 255;
    int h0 = (t >> 4) << 3, w0 = (t & 15) << 3;

    __shared__ __align__(16) char smem[37008];
    ushort* tile = (ushort*)smem;
    float* offl = (float*)(smem + 32400);

    const float* xb = x + ((long)b << 20);

    if (tid < 450) {
        int pos = tid >> 1, ch = (tid & 1) << 5;
        int ty = pos / 15, tx = pos - ty * 15;
        int y = h0 - 3 + ty, xx = w0 - 3 + tx;
        bool valid = ((unsigned)y < 128u) & ((unsigned)xx < 128u);
        int yc = min(max(y, 0), 127), xc = min(max(xx, 0), 127);
        const float* gp = xb + ((long)ch << 14) + (yc << 7) + xc;
        uint4* trow = (uint4*)&tile[pos * 72 + ch];
#pragma unroll
        for (int c8 = 0; c8 < 4; ++c8) {
            const float* g8 = gp + (c8 << 17);
            float v[8];
#pragma unroll
            for (int j = 0; j < 8; ++j) v[j] = valid ? g8[j << 14] : 0.f;
            uint4 d;
            d.x = (uint)f2bf(v[0]) | ((uint)f2bf(v[1]) << 16);
            d.y = (uint)f2bf(v[2]) | ((uint)f2bf(v[3]) << 16);
            d.z = (uint)f2bf(v[4]) | ((uint)f2bf(v[5]) << 16);
            d.w = (uint)f2bf(v[6]) | ((uint)f2bf(v[7]) << 16);
            trow[c8] = d;
        }
    }
    __syncthreads();

    int l15 = lane & 15, lq = lane >> 4;
    int p1 = (wq << 4) + l15;
    int plh = p1 >> 3, plw = p1 & 7;

    float4x oacc = {0.f, 0.f, 0.f, 0.f};
#pragma unroll
    for (int k2 = 0; k2 < 9; ++k2) {
        int kh = k2 / 3, kw = k2 - kh * 3;
        int pos = (plh + 2 + kh) * 15 + (plw + 2 + kw);
        int abase = pos * 72 + (lq << 3);
#pragma unroll
        for (int hf = 0; hf < 2; ++hf) {
            int kk = k2 * 2 + hf;
            short8x a = *(const short8x*)&tile[abase + hf * 32];
            short8x bo = *(const short8x*)&Bo[(kk * 2 + half) * 512 + (lane << 3)];
            oacc = __builtin_amdgcn_mfma_f32_16x16x32_bf16(a, bo, oacc, 0, 0, 0);
        }
    }
    {
        int n = (half << 4) + l15;
        if (n < 18) {
            float bo = boff[n];
#pragma unroll
            for (int r = 0; r < 4; ++r) {
                int p = (wq << 4) + (lq << 2) + r;
                offl[p * 18 + n] = oacc[r] + bo;
            }
        }
    }
    __syncthreads();

    float2 offr[9];
    uint oobmask = 0;
#pragma unroll
    for (int k2 = 0; k2 < 9; ++k2) {
        offr[k2] = *(const float2*)&offl[p1 * 18 + k2 * 2];
        const int kh = k2 / 3, kw = k2 - kh * 3;
        float sy = (float)(plh + 2 + kh) + offr[k2].x;
        float sx = (float)(plw + 2 + kw) + offr[k2].y;
        int by = (int)floorf(sy), bx = (int)floorf(sx);
        bool oob = ((unsigned)by > 13u) | ((unsigned)bx > 13u);
        oobmask |= oob ? (1u << k2) : 0u;
    }

    float4x acc[4];
#pragma unroll
    for (int nt = 0; nt < 4; ++nt) acc[nt] = (float4x){0.f, 0.f, 0.f, 0.f};

#pragma unroll
    for (int k2 = 0; k2 < 9; ++k2) {
        const int kh = k2 / 3, kw = k2 - kh * 3;
        float sy = (float)(plh + 2 + kh) + offr[k2].x;
        float sx = (float)(plw + 2 + kw) + offr[k2].y;
        float yf = floorf(sy), xf = floorf(sx);
        int by = (int)yf, bx = (int)xf;
        float wy1 = sy - yf, wx1 = sx - xf;
        float wy0 = 1.f - wy1, wx0 = 1.f - wx1;
        float w00 = wy0 * wx0, w01 = wy0 * wx1;
        float w10 = wy1 * wx0, w11 = wy1 * wx1;
        int byc = min(max(by, 0), 13), bxc = min(max(bx, 0), 13);
        int cb = (byc * 15 + bxc) * 72 + (lq << 3) + (half << 5);

        int kk = k2 * 2 + half;
        short8x c00 = *(const short8x*)&tile[cb];
        short8x c01 = *(const short8x*)&tile[cb + 72];
        short8x c10 = *(const short8x*)&tile[cb + 72 * 15];
        short8x c11 = *(const short8x*)&tile[cb + 72 * 16];
        float s[8];
#pragma unroll
        for (int j = 0; j < 8; ++j) {
            s[j] = w00 * bf2f((ushort)c00[j]) + w01 * bf2f((ushort)c01[j])
                 + w10 * bf2f((ushort)c10[j]) + w11 * bf2f((ushort)c11[j]);
        }
        union { short8x v; ushort u[8]; } A;
#pragma unroll
        for (int j = 0; j < 8; ++j) A.u[j] = f2bf(s[j]);
#pragma unroll
        for (int nt = 0; nt < 4; ++nt) {
            short8x bw = *(const short8x*)&Bd[(kk * 4 + nt) * 512 + (lane << 3)];
            acc[nt] = __builtin_amdgcn_mfma_f32_16x16x32_bf16(A.v, bw, acc[nt], 0, 0, 0);
        }
    }

    if (__any(oobmask != 0)) {
#pragma unroll 1
        for (int k2 = 0; k2 < 9; ++k2) {
            if (!__any((oobmask >> k2) & 1)) continue;
            bool oob = (oobmask >> k2) & 1;
            const int kh = k2 / 3, kw = k2 - kh * 3;
            float2 od = *(const float2*)&offl[p1 * 18 + k2 * 2];
            float sy = (float)(plh + 2 + kh) + od.x;
            float sx = (float)(plw + 2 + kw) + od.y;
            float yf = floorf(sy), xf = floorf(sx);
            int by = (int)yf, bx = (int)xf;
            float wy1 = sy - yf, wx1 = sx - xf;
            float wy0 = 1.f - wy1, wx0 = 1.f - wx1;
            float w00 = wy0 * wx0, w01 = wy0 * wx1;
            float w10 = wy1 * wx0, w11 = wy1 * wx1;
            int byc = min(max(by, 0), 13), bxc = min(max(bx, 0), 13);
            int cb = (byc * 15 + bxc) * 72 + (lq << 3) + (half << 5);
            int y0g = by + h0 - 3, x0g = bx + w0 - 3;
            int y1g = y0g + 1, x1g = x0g + 1;
            float m00 = ((unsigned)y0g < 128u && (unsigned)x0g < 128u) ? w00 : 0.f;
            float m01 = ((unsigned)y0g < 128u && (unsigned)x1g < 128u) ? w01 : 0.f;
            float m10 = ((unsigned)y1g < 128u && (unsigned)x0g < 128u) ? w10 : 0.f;
            float m11 = ((unsigned)y1g < 128u && (unsigned)x1g < 128u) ? w11 : 0.f;
            int y0c = min(max(y0g, 0), 127), y1c = min(max(y1g, 0), 127);
            int x0c = min(max(x0g, 0), 127), x1c = min(max(x1g, 0), 127);
            int i00 = (y0c << 7) + x0c, i01 = (y0c << 7) + x1c;
            int i10 = (y1c << 7) + x0c, i11 = (y1c << 7) + x1c;
            int kk = k2 * 2 + half;
            int cin0 = (half << 5) + (lq << 3);
            short8x c00 = *(const short8x*)&tile[cb];
            short8x c01 = *(const short8x*)&tile[cb + 72];
            short8x c10 = *(const short8x*)&tile[cb + 72 * 15];
            short8x c11 = *(const short8x*)&tile[cb + 72 * 16];
            float d[8];
#pragma unroll
            for (int j = 0; j < 8; ++j) {
                float sl = w00 * bf2f((ushort)c00[j]) + w01 * bf2f((ushort)c01[j])
                         + w10 * bf2f((ushort)c10[j]) + w11 * bf2f((ushort)c11[j]);
                const float* xp = xb + ((long)(cin0 + j) << 14);
                float sg = m00 * xp[i00] + m01 * xp[i01]
                         + m10 * xp[i10] + m11 * xp[i11];
                d[j] = oob ? (sg - sl) : 0.f;
            }
            union { short8x v; ushort u[8]; } A;
#pragma unroll
            for (int j = 0; j < 8; ++j) A.u[j] = f2bf(d[j]);
#pragma unroll
            for (int nt = 0; nt < 4; ++nt) {
                short8x bw = *(const short8x*)&Bd[(kk * 4 + nt) * 512 + (lane << 3)];
                acc[nt] = __builtin_amdgcn_mfma_f32_16x16x32_bf16(A.v, bw, acc[nt], 0, 0, 0);
            }
        }
    }

    __syncthreads();
    float* red = (float*)smem;
    if (half == 1) {
#pragma unroll
        for (int nt = 0; nt < 4; ++nt)
#pragma unroll
            for (int r = 0; r < 4; ++r) {
                int p = (wq << 4) + (lq << 2) + r;
                red[p * 65 + (nt << 4) + l15] = acc[nt][r];
            }
    }
    __syncthreads();
    if (half == 0) {
#pragma unroll
        for (int nt = 0; nt < 4; ++nt)
#pragma unroll
            for (int r = 0; r < 4; ++r) {
                int p = (wq << 4) + (lq << 2) + r;
                red[p * 65 + (nt << 4) + l15] += acc[nt][r];
            }
    }
    __syncthreads();

    {
        int n = tid >> 3, q = tid & 7;
        float bd = bdef[n];
        float* dst = out + (((long)(b * 64 + n)) << 14) + ((h0 + q) << 7) + w0;
        float v[8];
#pragma unroll
        for (int c = 0; c < 8; ++c) v[c] = red[(q * 8 + c) * 65 + n] + bd;
        float4x s0 = {v[0], v[1], v[2], v[3]};
        float4x s1 = {v[4], v[5], v[6], v[7]};
        *(float4x*)(dst) = s0;
        *(float4x*)(dst + 4) = s1;
    }
}

// ---------------------------------------------------------------------------
extern "C" void kernel_launch(void* const* d_in, const int* in_sizes, int n_in,
                              void* d_out, int out_size, void* d_ws, size_t ws_size,
                              hipStream_t stream) {
    const float* x     = (const float*)d_in[0];  // (4,64,128,128)
    const float* w_off = (const float*)d_in[1];  // (18,64,3,3)
    const float* b_off = (const float*)d_in[2];  // (18,)
    const float* w_def = (const float*)d_in[3];  // (64,64,3,3)
    const float* b_def = (const float*)d_in[4];  // (64,)
    float* out = (float*)d_out;                  // (4,64,128,128)

    const size_t NEED = 8388608ull + 73728ull + 36864ull + 16ull;
    if (ws_size >= NEED) {
        // fast path: xbf 8 MiB | Bd 73728 B | Bo 36864 B | zero page 16 B
        ushort* xbf = (ushort*)d_ws;                          // 4*16384*64 bf16
        ushort* Bd  = (ushort*)((char*)d_ws + 8388608);       // 36864 bf16
        ushort* Bo  = Bd + 36864;                             // 18432 bf16
        uint*   zp  = (uint*)((char*)d_ws + 8388608 + 73728 + 36864);
        hipLaunchKernelGGL(pack_all, dim3(944), dim3(128), 0, stream,
                           x, w_def, w_off, xbf, Bd, Bo, zp);
        hipLaunchKernelGGL(dcn_fused, dim3(1024), dim3(512), 0, stream,
                           x, xbf, Bd, Bo, b_off, b_def, (const ushort*)zp, out);
    } else {
        // fallback: verbatim R12 (proven)
        ushort* Bd = (ushort*)d_ws;                  // 36864 bf16 = 73728 B
        ushort* Bo = Bd + 36864;                     // 18432 bf16 = 36864 B
        hipLaunchKernelGGL(pack_weights, dim3(216), dim3(256), 0, stream,
                           w_def, w_off, Bd, Bo);
        hipLaunchKernelGGL(dcn_fused_fb, dim3(1024), dim3(512), 0, stream,
                           x, Bd, Bo, b_off, b_def, out);
    }
}

// Round 7
// 104.220 us; speedup vs baseline: 2.6669x; 1.0655x over previous
//
#include <hip/hip_runtime.h>

// B=4, CIN=COUT=64, H=W=128, 3x3 deformable conv, fp32 in/out.
// R19 = R14 (best: 105.6 us) + issue-width cuts:
//  - (512,4) restored: R18 proved 8 waves/SIMD TLP > 4 waves + 128 VGPR ILP.
//  - stage-2 A-pack via v_cvt_pk_bf16_f32 (4 instrs vs 8 f2bf ~= 24-32 VALU)
//    per k2 step; RNE rounding matches f2bf.
//  - epilogue: 3 barriers -> 2. Halves write disjoint red0/red1 (each
//    64x65 f32 = 16640 B, overlaying dead tile+offl); store adds both.
//    Removes the RMW pass and one convoy barrier.
// Knob ladder (measured): __launch_bounds__(512,N) -> VGPR cap 256/N.
//  (512,8)=32 spills; (512,4)=64 fits single-tile; (512,2)=128 (R17/R18).

typedef __attribute__((ext_vector_type(8))) short short8x;
typedef __attribute__((ext_vector_type(4))) float float4x;
typedef unsigned short ushort;
typedef unsigned int uint;

__device__ __forceinline__ ushort f2bf(float f) {
    uint b = __float_as_uint(f);
    b += 0x7fffu + ((b >> 16) & 1u);
    return (ushort)(b >> 16);
}
__device__ __forceinline__ float bf2f(ushort u) {
    return __uint_as_float(((uint)u) << 16);
}

__device__ __forceinline__ void gload16(const void* g, void* l) {
    __builtin_amdgcn_global_load_lds(
        (const __attribute__((address_space(1))) void*)g,
        (__attribute__((address_space(3))) void*)l, 16, 0, 0);
}

// ===========================================================================
// FAST PATH (requires ws_size >= 8.5 MB)
// ===========================================================================

__global__ __launch_bounds__(128) void pack_all(
    const float* __restrict__ x, const float* __restrict__ w_def,
    const float* __restrict__ w_off, ushort* __restrict__ xbf,
    ushort* __restrict__ Bd, ushort* __restrict__ Bo, uint* __restrict__ zp) {
    int tid = threadIdx.x, bid = blockIdx.x;
    if (bid < 512) {
        int p = (bid << 7) + tid;          // 0..65535 pixel id
        if (p == 0) { zp[0] = 0; zp[1] = 0; zp[2] = 0; zp[3] = 0; }
        int b = p >> 14;
        const float* src = x + ((long)b << 20) + (p & 16383);
        ushort* dst = xbf + ((long)p << 6);
        float v[64];
#pragma unroll
        for (int c = 0; c < 64; ++c) v[c] = src[(long)c << 14];
#pragma unroll
        for (int g = 0; g < 8; ++g) {
            uint4 d;
            d.x = (uint)f2bf(v[g * 8 + 0]) | ((uint)f2bf(v[g * 8 + 1]) << 16);
            d.y = (uint)f2bf(v[g * 8 + 2]) | ((uint)f2bf(v[g * 8 + 3]) << 16);
            d.z = (uint)f2bf(v[g * 8 + 4]) | ((uint)f2bf(v[g * 8 + 5]) << 16);
            d.w = (uint)f2bf(v[g * 8 + 6]) | ((uint)f2bf(v[g * 8 + 7]) << 16);
            *(uint4*)(dst + (g << 3)) = d;
        }
    } else {
        int idx = ((bid - 512) << 7) + tid;   // 0..55295
        if (idx < 36864) {
            int i = idx & 7;
            int lane = (idx >> 3) & 63;
            int nt = (idx >> 9) & 3;
            int kk = idx >> 11;
            int n = (nt << 4) + (lane & 15);
            int k2 = kk >> 1;
            int cin = ((kk & 1) << 5) + ((lane >> 4) << 3) + i;
            Bd[idx] = f2bf(w_def[(n * 64 + cin) * 9 + k2]);
        } else {
            int d = idx - 36864;
            int i = d & 7;
            int lane = (d >> 3) & 63;
            int nt = (d >> 9) & 1;
            int kk = d >> 10;
            int n = (nt << 4) + (lane & 15);
            int k2 = kk >> 1;
            int cin = ((kk & 1) << 5) + ((lane >> 4) << 3) + i;
            Bo[d] = (n < 18) ? f2bf(w_off[(n * 64 + cin) * 9 + k2]) : (ushort)0;
        }
    }
}

// ---------------------------------------------------------------------------
// Fused kernel (fast path). Block = 8x8 pixel tile, 512 threads = 8 waves.
// wq = wv&3 owns pixels 16wq..16wq+15; half = wv>>2 owns cins 32half..+31.
// ---------------------------------------------------------------------------
__global__ __launch_bounds__(512, 4) void dcn_fused(
    const float* __restrict__ x, const ushort* __restrict__ xbf,
    const ushort* __restrict__ Bd, const ushort* __restrict__ Bo,
    const float* __restrict__ boff, const float* __restrict__ bdef,
    const ushort* __restrict__ zp, float* __restrict__ out) {

    int tid = threadIdx.x;
    int lane = tid & 63, wv = tid >> 6;
    int wq = wv & 3, half = wv >> 2;
    // XCD-aware swizzle: 1024 blocks % 8 == 0 -> bijective.
    int raw = blockIdx.x;
    int blk = ((raw & 7) << 7) + (raw >> 3);
    int b = blk >> 8, t = blk & 255;
    int h0 = (t >> 4) << 3, w0 = (t & 15) << 3;

    // Manual shared layout (37008 B): tile 32400 B | offl 4608 B.
    // Staging writes 32 KiB linearly (chunk 31 spills 368 B into offl's
    // start; offl is fully rewritten by stage-1 before any read).
    // Epilogue overlays red0 [0,16640) and red1 [16640,33280) — tile and
    // offl are both dead by then (offl last read in cold pass, pre-barrier).
    __shared__ __align__(16) char smem[37008];
    ushort* tile = (ushort*)smem;              // [pos(225) stride 72][cin 64]
    float* offl = (float*)(smem + 32400);      // [px 64][ch 18]

    const float* xb = x + ((long)b << 20);

    // ---- stage halo: 32 chunks x 1 KiB via global_load_lds dwordx4.
    {
        const ushort* xb2 = xbf + ((long)b << 20);  // b*16384 pixels * 64 ch
#pragma unroll
        for (int c = 0; c < 4; ++c) {
            int chunk = wv + (c << 3);
            int o4 = (chunk << 6) + lane;           // byte/16, 0..2047
            int pos = (o4 * 7282) >> 16;            // /9 (exact, o4<=2047)
            int slot = o4 - pos * 9;
            int ty = (pos * 4370) >> 16;            // /15 (exact, pos<=227)
            int tx = pos - ty * 15;
            int y = h0 - 3 + ty, xx = w0 - 3 + tx;
            bool valid = ((unsigned)y < 128u) & ((unsigned)xx < 128u) & (slot < 8);
            const ushort* gp = valid
                ? xb2 + (((y << 7) + xx) << 6) + (slot << 3)
                : zp;
            gload16(gp, smem + (chunk << 10));
        }
    }
    __syncthreads();   // waits vmcnt(0) before barrier

    int l15 = lane & 15, lq = lane >> 4;
    int p1 = (wq << 4) + l15;          // this lane's A-row pixel
    int plh = p1 >> 3, plw = p1 & 7;

    // ---- stage 1: offset conv via MFMA, N-split.
    float4x oacc = {0.f, 0.f, 0.f, 0.f};
#pragma unroll
    for (int k2 = 0; k2 < 9; ++k2) {
        int kh = k2 / 3, kw = k2 - kh * 3;
        int pos = (plh + 2 + kh) * 15 + (plw + 2 + kw);
        int abase = pos * 72 + (lq << 3);
#pragma unroll
        for (int hf = 0; hf < 2; ++hf) {
            int kk = k2 * 2 + hf;
            short8x a = *(const short8x*)&tile[abase + hf * 32];
            short8x bo = *(const short8x*)&Bo[(kk * 2 + half) * 512 + (lane << 3)];
            oacc = __builtin_amdgcn_mfma_f32_16x16x32_bf16(a, bo, oacc, 0, 0, 0);
        }
    }
    {   // scatter D (col n = 16*half + l15, row = lq*4+r) + bias -> offl
        int n = (half << 4) + l15;
        if (n < 18) {
            float bo = boff[n];
#pragma unroll
            for (int r = 0; r < 4; ++r) {
                int p = (wq << 4) + (lq << 2) + r;
                offl[p * 18 + n] = oacc[r] + bo;
            }
        }
    }
    __syncthreads();

    // ---- offsets to registers (constant-indexed only) + oob mask
    float2 offr[9];
    uint oobmask = 0;
#pragma unroll
    for (int k2 = 0; k2 < 9; ++k2) {
        offr[k2] = *(const float2*)&offl[p1 * 18 + k2 * 2];
        const int kh = k2 / 3, kw = k2 - kh * 3;
        float sy = (float)(plh + 2 + kh) + offr[k2].x;
        float sx = (float)(plw + 2 + kw) + offr[k2].y;
        int by = (int)floorf(sy), bx = (int)floorf(sx);
        bool oob = ((unsigned)by > 13u) | ((unsigned)bx > 13u);
        oobmask |= oob ? (1u << k2) : 0u;
    }

    // ---- stage 2: 9 steps over this wave's cin-half
    float4x acc[4];
#pragma unroll
    for (int nt = 0; nt < 4; ++nt) acc[nt] = (float4x){0.f, 0.f, 0.f, 0.f};

#pragma unroll
    for (int k2 = 0; k2 < 9; ++k2) {
        const int kh = k2 / 3, kw = k2 - kh * 3;
        float sy = (float)(plh + 2 + kh) + offr[k2].x;
        float sx = (float)(plw + 2 + kw) + offr[k2].y;
        float yf = floorf(sy), xf = floorf(sx);
        int by = (int)yf, bx = (int)xf;
        float wy1 = sy - yf, wx1 = sx - xf;
        float wy0 = 1.f - wy1, wx0 = 1.f - wx1;
        float w00 = wy0 * wx0, w01 = wy0 * wx1;
        float w10 = wy1 * wx0, w11 = wy1 * wx1;
        int byc = min(max(by, 0), 13), bxc = min(max(bx, 0), 13);
        int cb = (byc * 15 + bxc) * 72 + (lq << 3) + (half << 5);

        int kk = k2 * 2 + half;
        short8x c00 = *(const short8x*)&tile[cb];
        short8x c01 = *(const short8x*)&tile[cb + 72];
        short8x c10 = *(const short8x*)&tile[cb + 72 * 15];
        short8x c11 = *(const short8x*)&tile[cb + 72 * 16];
        float s[8];
#pragma unroll
        for (int j = 0; j < 8; ++j) {
            s[j] = w00 * bf2f((ushort)c00[j]) + w01 * bf2f((ushort)c01[j])
                 + w10 * bf2f((ushort)c10[j]) + w11 * bf2f((ushort)c11[j]);
        }
        // pack 8 f32 -> 8 bf16 via 4x v_cvt_pk_bf16_f32 (RNE, same as f2bf)
        union { short8x v; uint w[4]; } A;
#pragma unroll
        for (int jj = 0; jj < 4; ++jj)
            asm("v_cvt_pk_bf16_f32 %0, %1, %2"
                : "=v"(A.w[jj]) : "v"(s[2 * jj]), "v"(s[2 * jj + 1]));
#pragma unroll
        for (int nt = 0; nt < 4; ++nt) {
            short8x bw = *(const short8x*)&Bd[(kk * 4 + nt) * 512 + (lane << 3)];
            acc[nt] = __builtin_amdgcn_mfma_f32_16x16x32_bf16(A.v, bw, acc[nt], 0, 0, 0);
        }
    }

    // ---- cold exactness pass (own half): out-of-tile samples (~8 sigma,
    // never taken on this data).
    if (__any(oobmask != 0)) {
#pragma unroll 1
        for (int k2 = 0; k2 < 9; ++k2) {
            if (!__any((oobmask >> k2) & 1)) continue;
            bool oob = (oobmask >> k2) & 1;
            const int kh = k2 / 3, kw = k2 - kh * 3;
            float2 od = *(const float2*)&offl[p1 * 18 + k2 * 2];
            float sy = (float)(plh + 2 + kh) + od.x;
            float sx = (float)(plw + 2 + kw) + od.y;
            float yf = floorf(sy), xf = floorf(sx);
            int by = (int)yf, bx = (int)xf;
            float wy1 = sy - yf, wx1 = sx - xf;
            float wy0 = 1.f - wy1, wx0 = 1.f - wx1;
            float w00 = wy0 * wx0, w01 = wy0 * wx1;
            float w10 = wy1 * wx0, w11 = wy1 * wx1;
            int byc = min(max(by, 0), 13), bxc = min(max(bx, 0), 13);
            int cb = (byc * 15 + bxc) * 72 + (lq << 3) + (half << 5);
            int y0g = by + h0 - 3, x0g = bx + w0 - 3;
            int y1g = y0g + 1, x1g = x0g + 1;
            float m00 = ((unsigned)y0g < 128u && (unsigned)x0g < 128u) ? w00 : 0.f;
            float m01 = ((unsigned)y0g < 128u && (unsigned)x1g < 128u) ? w01 : 0.f;
            float m10 = ((unsigned)y1g < 128u && (unsigned)x0g < 128u) ? w10 : 0.f;
            float m11 = ((unsigned)y1g < 128u && (unsigned)x1g < 128u) ? w11 : 0.f;
            int y0c = min(max(y0g, 0), 127), y1c = min(max(y1g, 0), 127);
            int x0c = min(max(x0g, 0), 127), x1c = min(max(x1g, 0), 127);
            int i00 = (y0c << 7) + x0c, i01 = (y0c << 7) + x1c;
            int i10 = (y1c << 7) + x0c, i11 = (y1c << 7) + x1c;
            int kk = k2 * 2 + half;
            int cin0 = (half << 5) + (lq << 3);
            short8x c00 = *(const short8x*)&tile[cb];
            short8x c01 = *(const short8x*)&tile[cb + 72];
            short8x c10 = *(const short8x*)&tile[cb + 72 * 15];
            short8x c11 = *(const short8x*)&tile[cb + 72 * 16];
            float d[8];
#pragma unroll
            for (int j = 0; j < 8; ++j) {
                float sl = w00 * bf2f((ushort)c00[j]) + w01 * bf2f((ushort)c01[j])
                         + w10 * bf2f((ushort)c10[j]) + w11 * bf2f((ushort)c11[j]);
                const float* xp = xb + ((long)(cin0 + j) << 14);
                float sg = m00 * xp[i00] + m01 * xp[i01]
                         + m10 * xp[i10] + m11 * xp[i11];
                d[j] = oob ? (sg - sl) : 0.f;
            }
            union { short8x v; ushort u[8]; } A;
#pragma unroll
            for (int j = 0; j < 8; ++j) A.u[j] = f2bf(d[j]);
#pragma unroll
            for (int nt = 0; nt < 4; ++nt) {
                short8x bw = *(const short8x*)&Bd[(kk * 4 + nt) * 512 + (lane << 3)];
                acc[nt] = __builtin_amdgcn_mfma_f32_16x16x32_bf16(A.v, bw, acc[nt], 0, 0, 0);
            }
        }
    }

    // ---- reduce: both halves write disjoint red regions, one barrier,
    // store adds them. red0 [0,16640), red1 [16640,33280) — 64x65 f32 each
    // (pad-65: conflict-free; 33280 <= 37008, offl/tile dead by now).
    __syncthreads();
    float* redh = (float*)(smem + (half ? 16640 : 0));
#pragma unroll
    for (int nt = 0; nt < 4; ++nt)
#pragma unroll
        for (int r = 0; r < 4; ++r) {
            int p = (wq << 4) + (lq << 2) + r;
            redh[p * 65 + (nt << 4) + l15] = acc[nt][r];
        }
    __syncthreads();

    // ---- store: 512 threads, thread = (cout n, row q); 2x float4 per thread
    {
        float* red0 = (float*)smem;
        float* red1 = (float*)(smem + 16640);
        int n = tid >> 3, q = tid & 7;
        float bd = bdef[n];
        float* dst = out + (((long)(b * 64 + n)) << 14) + ((h0 + q) << 7) + w0;
        float v[8];
#pragma unroll
        for (int c = 0; c < 8; ++c) {
            int idx = (q * 8 + c) * 65 + n;
            v[c] = red0[idx] + red1[idx] + bd;
        }
        float4x s0 = {v[0], v[1], v[2], v[3]};
        float4x s1 = {v[4], v[5], v[6], v[7]};
        *(float4x*)(dst) = s0;
        *(float4x*)(dst + 4) = s1;
    }
}

// ===========================================================================
// FALLBACK PATH (verbatim R12, harness-proven at 110.4 µs; needs ~111 KB ws)
// ===========================================================================

__global__ __launch_bounds__(256) void pack_weights(
    const float* __restrict__ w_def, const float* __restrict__ w_off,
    ushort* __restrict__ Bd, ushort* __restrict__ Bo) {
    int idx = blockIdx.x * 256 + threadIdx.x;
    if (idx < 36864) {
        int i = idx & 7;
        int lane = (idx >> 3) & 63;
        int nt = (idx >> 9) & 3;
        int kk = idx >> 11;
        int n = (nt << 4) + (lane & 15);
        int k2 = kk >> 1;
        int cin = ((kk & 1) << 5) + ((lane >> 4) << 3) + i;
        Bd[idx] = f2bf(w_def[(n * 64 + cin) * 9 + k2]);
    } else if (idx < 36864 + 18432) {
        int d = idx - 36864;
        int i = d & 7;
        int lane = (d >> 3) & 63;
        int nt = (d >> 9) & 1;
        int kk = d >> 10;
        int n = (nt << 4) + (lane & 15);
        int k2 = kk >> 1;
        int cin = ((kk & 1) << 5) + ((lane >> 4) << 3) + i;
        Bo[d] = (n < 18) ? f2bf(w_off[(n * 64 + cin) * 9 + k2]) : (ushort)0;
    }
}

__global__ __launch_bounds__(512, 4) void dcn_fused_fb(
    const float* __restrict__ x, const ushort* __restrict__ Bd,
    const ushort* __restrict__ Bo, const float* __restrict__ boff,
    const float* __restrict__ bdef, float* __restrict__ out) {

    int tid = threadIdx.x;
    int lane = tid & 63, wv = tid >> 6;
    int wq = wv & 3, half = wv >> 2;
    int blk = blockIdx.x;
    int b = blk >> 8, t = blk & 255;
    int h0 = (t >> 4) << 3, w0 = (t & 15) << 3;

    __shared__ __align__(16) char smem[37008];
    ushort* tile = (ushort*)smem;
    float* offl = (float*)(smem + 32400);

    const float* xb = x + ((long)b << 20);

    if (tid < 450) {
        int pos = tid >> 1, ch = (tid & 1) << 5;
        int ty = pos / 15, tx = pos - ty * 15;
        int y = h0 - 3 + ty, xx = w0 - 3 + tx;
        bool valid = ((unsigned)y < 128u) & ((unsigned)xx < 128u);
        int yc = min(max(y, 0), 127), xc = min(max(xx, 0), 127);
        const float* gp = xb + ((long)ch << 14) + (yc << 7) + xc;
        uint4* trow = (uint4*)&tile[pos * 72 + ch];
#pragma unroll
        for (int c8 = 0; c8 < 4; ++c8) {
            const float* g8 = gp + (c8 << 17);
            float v[8];
#pragma unroll
            for (int j = 0; j < 8; ++j) v[j] = valid ? g8[j << 14] : 0.f;
            uint4 d;
            d.x = (uint)f2bf(v[0]) | ((uint)f2bf(v[1]) << 16);
            d.y = (uint)f2bf(v[2]) | ((uint)f2bf(v[3]) << 16);
            d.z = (uint)f2bf(v[4]) | ((uint)f2bf(v[5]) << 16);
            d.w = (uint)f2bf(v[6]) | ((uint)f2bf(v[7]) << 16);
            trow[c8] = d;
        }
    }
    __syncthreads();

    int l15 = lane & 15, lq = lane >> 4;
    int p1 = (wq << 4) + l15;
    int plh = p1 >> 3, plw = p1 & 7;

    float4x oacc = {0.f, 0.f, 0.f, 0.f};
#pragma unroll
    for (int k2 = 0; k2 < 9; ++k2) {
        int kh = k2 / 3, kw = k2 - kh * 3;
        int pos = (plh + 2 + kh) * 15 + (plw + 2 + kw);
        int abase = pos * 72 + (lq << 3);
#pragma unroll
        for (int hf = 0; hf < 2; ++hf) {
            int kk = k2 * 2 + hf;
            short8x a = *(const short8x*)&tile[abase + hf * 32];
            short8x bo = *(const short8x*)&Bo[(kk * 2 + half) * 512 + (lane << 3)];
            oacc = __builtin_amdgcn_mfma_f32_16x16x32_bf16(a, bo, oacc, 0, 0, 0);
        }
    }
    {
        int n = (half << 4) + l15;
        if (n < 18) {
            float bo = boff[n];
#pragma unroll
            for (int r = 0; r < 4; ++r) {
                int p = (wq << 4) + (lq << 2) + r;
                offl[p * 18 + n] = oacc[r] + bo;
            }
        }
    }
    __syncthreads();

    float2 offr[9];
    uint oobmask = 0;
#pragma unroll
    for (int k2 = 0; k2 < 9; ++k2) {
        offr[k2] = *(const float2*)&offl[p1 * 18 + k2 * 2];
        const int kh = k2 / 3, kw = k2 - kh * 3;
        float sy = (float)(plh + 2 + kh) + offr[k2].x;
        float sx = (float)(plw + 2 + kw) + offr[k2].y;
        int by = (int)floorf(sy), bx = (int)floorf(sx);
        bool oob = ((unsigned)by > 13u) | ((unsigned)bx > 13u);
        oobmask |= oob ? (1u << k2) : 0u;
    }

    float4x acc[4];
#pragma unroll
    for (int nt = 0; nt < 4; ++nt) acc[nt] = (float4x){0.f, 0.f, 0.f, 0.f};

#pragma unroll
    for (int k2 = 0; k2 < 9; ++k2) {
        const int kh = k2 / 3, kw = k2 - kh * 3;
        float sy = (float)(plh + 2 + kh) + offr[k2].x;
        float sx = (float)(plw + 2 + kw) + offr[k2].y;
        float yf = floorf(sy), xf = floorf(sx);
        int by = (int)yf, bx = (int)xf;
        float wy1 = sy - yf, wx1 = sx - xf;
        float wy0 = 1.f - wy1, wx0 = 1.f - wx1;
        float w00 = wy0 * wx0, w01 = wy0 * wx1;
        float w10 = wy1 * wx0, w11 = wy1 * wx1;
        int byc = min(max(by, 0), 13), bxc = min(max(bx, 0), 13);
        int cb = (byc * 15 + bxc) * 72 + (lq << 3) + (half << 5);

        int kk = k2 * 2 + half;
        short8x c00 = *(const short8x*)&tile[cb];
        short8x c01 = *(const short8x*)&tile[cb + 72];
        short8x c10 = *(const short8x*)&tile[cb + 72 * 15];
        short8x c11 = *(const short8x*)&tile[cb + 72 * 16];
        float s[8];
#pragma unroll
        for (int j = 0; j < 8; ++j) {
            s[j] = w00 * bf2f((ushort)c00[j]) + w01 * bf2f((ushort)c01[j])
                 + w10 * bf2f((ushort)c10[j]) + w11 * bf2f((ushort)c11[j]);
        }
        union { short8x v; ushort u[8]; } A;
#pragma unroll
        for (int j = 0; j < 8; ++j) A.u[j] = f2bf(s[j]);
#pragma unroll
        for (int nt = 0; nt < 4; ++nt) {
            short8x bw = *(const short8x*)&Bd[(kk * 4 + nt) * 512 + (lane << 3)];
            acc[nt] = __builtin_amdgcn_mfma_f32_16x16x32_bf16(A.v, bw, acc[nt], 0, 0, 0);
        }
    }

    if (__any(oobmask != 0)) {
#pragma unroll 1
        for (int k2 = 0; k2 < 9; ++k2) {
            if (!__any((oobmask >> k2) & 1)) continue;
            bool oob = (oobmask >> k2) & 1;
            const int kh = k2 / 3, kw = k2 - kh * 3;
            float2 od = *(const float2*)&offl[p1 * 18 + k2 * 2];
            float sy = (float)(plh + 2 + kh) + od.x;
            float sx = (float)(plw + 2 + kw) + od.y;
            float yf = floorf(sy), xf = floorf(sx);
            int by = (int)yf, bx = (int)xf;
            float wy1 = sy - yf, wx1 = sx - xf;
            float wy0 = 1.f - wy1, wx0 = 1.f - wx1;
            float w00 = wy0 * wx0, w01 = wy0 * wx1;
            float w10 = wy1 * wx0, w11 = wy1 * wx1;
            int byc = min(max(by, 0), 13), bxc = min(max(bx, 0), 13);
            int cb = (byc * 15 + bxc) * 72 + (lq << 3) + (half << 5);
            int y0g = by + h0 - 3, x0g = bx + w0 - 3;
            int y1g = y0g + 1, x1g = x0g + 1;
            float m00 = ((unsigned)y0g < 128u && (unsigned)x0g < 128u) ? w00 : 0.f;
            float m01 = ((unsigned)y0g < 128u && (unsigned)x1g < 128u) ? w01 : 0.f;
            float m10 = ((unsigned)y1g < 128u && (unsigned)x0g < 128u) ? w10 : 0.f;
            float m11 = ((unsigned)y1g < 128u && (unsigned)x1g < 128u) ? w11 : 0.f;
            int y0c = min(max(y0g, 0), 127), y1c = min(max(y1g, 0), 127);
            int x0c = min(max(x0g, 0), 127), x1c = min(max(x1g, 0), 127);
            int i00 = (y0c << 7) + x0c, i01 = (y0c << 7) + x1c;
            int i10 = (y1c << 7) + x0c, i11 = (y1c << 7) + x1c;
            int kk = k2 * 2 + half;
            int cin0 = (half << 5) + (lq << 3);
            short8x c00 = *(const short8x*)&tile[cb];
            short8x c01 = *(const short8x*)&tile[cb + 72];
            short8x c10 = *(const short8x*)&tile[cb + 72 * 15];
            short8x c11 = *(const short8x*)&tile[cb + 72 * 16];
            float d[8];
#pragma unroll
            for (int j = 0; j < 8; ++j) {
                float sl = w00 * bf2f((ushort)c00[j]) + w01 * bf2f((ushort)c01[j])
                         + w10 * bf2f((ushort)c10[j]) + w11 * bf2f((ushort)c11[j]);
                const float* xp = xb + ((long)(cin0 + j) << 14);
                float sg = m00 * xp[i00] + m01 * xp[i01]
                         + m10 * xp[i10] + m11 * xp[i11];
                d[j] = oob ? (sg - sl) : 0.f;
            }
            union { short8x v; ushort u[8]; } A;
#pragma unroll
            for (int j = 0; j < 8; ++j) A.u[j] = f2bf(d[j]);
#pragma unroll
            for (int nt = 0; nt < 4; ++nt) {
                short8x bw = *(const short8x*)&Bd[(kk * 4 + nt) * 512 + (lane << 3)];
                acc[nt] = __builtin_amdgcn_mfma_f32_16x16x32_bf16(A.v, bw, acc[nt], 0, 0, 0);
            }
        }
    }

    __syncthreads();
    float* red = (float*)smem;
    if (half == 1) {
#pragma unroll
        for (int nt = 0; nt < 4; ++nt)
#pragma unroll
            for (int r = 0; r < 4; ++r) {
                int p = (wq << 4) + (lq << 2) + r;
                red[p * 65 + (nt << 4) + l15] = acc[nt][r];
            }
    }
    __syncthreads();
    if (half == 0) {
#pragma unroll
        for (int nt = 0; nt < 4; ++nt)
#pragma unroll
            for (int r = 0; r < 4; ++r) {
                int p = (wq << 4) + (lq << 2) + r;
                red[p * 65 + (nt << 4) + l15] += acc[nt][r];
            }
    }
    __syncthreads();

    {
        int n = tid >> 3, q = tid & 7;
        float bd = bdef[n];
        float* dst = out + (((long)(b * 64 + n)) << 14) + ((h0 + q) << 7) + w0;
        float v[8];
#pragma unroll
        for (int c = 0; c < 8; ++c) v[c] = red[(q * 8 + c) * 65 + n] + bd;
        float4x s0 = {v[0], v[1], v[2], v[3]};
        float4x s1 = {v[4], v[5], v[6], v[7]};
        *(float4x*)(dst) = s0;
        *(float4x*)(dst + 4) = s1;
    }
}

// ---------------------------------------------------------------------------
extern "C" void kernel_launch(void* const* d_in, const int* in_sizes, int n_in,
                              void* d_out, int out_size, void* d_ws, size_t ws_size,
                              hipStream_t stream) {
    const float* x     = (const float*)d_in[0];  // (4,64,128,128)
    const float* w_off = (const float*)d_in[1];  // (18,64,3,3)
    const float* b_off = (const float*)d_in[2];  // (18,)
    const float* w_def = (const float*)d_in[3];  // (64,64,3,3)
    const float* b_def = (const float*)d_in[4];  // (64,)
    float* out = (float*)d_out;                  // (4,64,128,128)

    const size_t NEED = 8388608ull + 73728ull + 36864ull + 16ull;
    if (ws_size >= NEED) {
        // fast path: xbf 8 MiB | Bd 73728 B | Bo 36864 B | zero page 16 B
        ushort* xbf = (ushort*)d_ws;                          // 4*16384*64 bf16
        ushort* Bd  = (ushort*)((char*)d_ws + 8388608);       // 36864 bf16
        ushort* Bo  = Bd + 36864;                             // 18432 bf16
        uint*   zp  = (uint*)((char*)d_ws + 8388608 + 73728 + 36864);
        hipLaunchKernelGGL(pack_all, dim3(944), dim3(128), 0, stream,
                           x, w_def, w_off, xbf, Bd, Bo, zp);
        hipLaunchKernelGGL(dcn_fused, dim3(1024), dim3(512), 0, stream,
                           x, xbf, Bd, Bo, b_off, b_def, (const ushort*)zp, out);
    } else {
        // fallback: verbatim R12 (proven)
        ushort* Bd = (ushort*)d_ws;                  // 36864 bf16 = 73728 B
        ushort* Bo = Bd + 36864;                     // 18432 bf16 = 36864 B
        hipLaunchKernelGGL(pack_weights, dim3(216), dim3(256), 0, stream,
                           w_def, w_off, Bd, Bo);
        hipLaunchKernelGGL(dcn_fused_fb, dim3(1024), dim3(512), 0, stream,
                           x, Bd, Bo, b_off, b_def, out);
    }
}

// Round 8
// 102.261 us; speedup vs baseline: 2.7180x; 1.0192x over previous
//
#include <hip/hip_runtime.h>

// B=4, CIN=COUT=64, H=W=128, 3x3 deformable conv, fp32 in/out.
// R20 = R19 with 8x4 tiles (convoy-breaker):
// R19 post-mortem: VALU issue accounts for ~25% of cycles (= measured
// VALUBusy); 75% idle with 8 resident waves -> barrier convoy (all waves of
// a block phase-locked). Fix: smaller blocks, more independent streams.
//  - 2048 blocks x 256 threads (4 waves). Tile = 8 rows x 4 cols,
//    halo 15x11 = 165 pos, LDS 26064 B -> 6 blocks/CU, 1 wave/SIMD/block
//    = 6 INDEPENDENT streams per SIMD (vs 4 correlated before).
//  - __launch_bounds__(256,4): VGPR cap 256/4 = 64 (proven no-spill budget;
//    per-wave body unchanged from R19).
//  - Keeps: xbf bf16 channel-last staging via global_load_lds, XCD swizzle,
//    v_cvt_pk_bf16_f32 A-pack, 2-barrier epilogue, cold exactness pass.

typedef __attribute__((ext_vector_type(8))) short short8x;
typedef __attribute__((ext_vector_type(4))) float float4x;
typedef unsigned short ushort;
typedef unsigned int uint;

__device__ __forceinline__ ushort f2bf(float f) {
    uint b = __float_as_uint(f);
    b += 0x7fffu + ((b >> 16) & 1u);
    return (ushort)(b >> 16);
}
__device__ __forceinline__ float bf2f(ushort u) {
    return __uint_as_float(((uint)u) << 16);
}

__device__ __forceinline__ void gload16(const void* g, void* l) {
    __builtin_amdgcn_global_load_lds(
        (const __attribute__((address_space(1))) void*)g,
        (__attribute__((address_space(3))) void*)l, 16, 0, 0);
}

// ===========================================================================
// FAST PATH (requires ws_size >= 8.5 MB)
// ===========================================================================

__global__ __launch_bounds__(128) void pack_all(
    const float* __restrict__ x, const float* __restrict__ w_def,
    const float* __restrict__ w_off, ushort* __restrict__ xbf,
    ushort* __restrict__ Bd, ushort* __restrict__ Bo, uint* __restrict__ zp) {
    int tid = threadIdx.x, bid = blockIdx.x;
    if (bid < 512) {
        int p = (bid << 7) + tid;          // 0..65535 pixel id
        if (p == 0) { zp[0] = 0; zp[1] = 0; zp[2] = 0; zp[3] = 0; }
        int b = p >> 14;
        const float* src = x + ((long)b << 20) + (p & 16383);
        ushort* dst = xbf + ((long)p << 6);
        float v[64];
#pragma unroll
        for (int c = 0; c < 64; ++c) v[c] = src[(long)c << 14];
#pragma unroll
        for (int g = 0; g < 8; ++g) {
            uint4 d;
            d.x = (uint)f2bf(v[g * 8 + 0]) | ((uint)f2bf(v[g * 8 + 1]) << 16);
            d.y = (uint)f2bf(v[g * 8 + 2]) | ((uint)f2bf(v[g * 8 + 3]) << 16);
            d.z = (uint)f2bf(v[g * 8 + 4]) | ((uint)f2bf(v[g * 8 + 5]) << 16);
            d.w = (uint)f2bf(v[g * 8 + 6]) | ((uint)f2bf(v[g * 8 + 7]) << 16);
            *(uint4*)(dst + (g << 3)) = d;
        }
    } else {
        int idx = ((bid - 512) << 7) + tid;   // 0..55295
        if (idx < 36864) {
            int i = idx & 7;
            int lane = (idx >> 3) & 63;
            int nt = (idx >> 9) & 3;
            int kk = idx >> 11;
            int n = (nt << 4) + (lane & 15);
            int k2 = kk >> 1;
            int cin = ((kk & 1) << 5) + ((lane >> 4) << 3) + i;
            Bd[idx] = f2bf(w_def[(n * 64 + cin) * 9 + k2]);
        } else {
            int d = idx - 36864;
            int i = d & 7;
            int lane = (d >> 3) & 63;
            int nt = (d >> 9) & 1;
            int kk = d >> 10;
            int n = (nt << 4) + (lane & 15);
            int k2 = kk >> 1;
            int cin = ((kk & 1) << 5) + ((lane >> 4) << 3) + i;
            Bo[d] = (n < 18) ? f2bf(w_off[(n * 64 + cin) * 9 + k2]) : (ushort)0;
        }
    }
}

// ---------------------------------------------------------------------------
// Fused kernel (fast path). Block = 8x4 pixel tile, 256 threads = 4 waves:
// wq = wv&1 owns pixels 16wq..16wq+15 (pixel p = row(p>>2), col(p&3));
// half = wv>>1 owns cins 32half..+31 (and n-group half in stage 1).
// Halo: 15 rows x 11 cols = 165 pos, stride 72 ushorts (144 B).
// LDS 26064 B: tile 23760 | offl 2304. Staging writes 24 chunks x 1 KiB
// linearly (last chunk spills 816 B into offl; offl rewritten by stage-1).
// Epilogue overlays red0 [0,8320), red1 [8320,16640) (32x65 f32 each).
// ---------------------------------------------------------------------------
__global__ __launch_bounds__(256, 4) void dcn_fused(
    const float* __restrict__ x, const ushort* __restrict__ xbf,
    const ushort* __restrict__ Bd, const ushort* __restrict__ Bo,
    const float* __restrict__ boff, const float* __restrict__ bdef,
    const ushort* __restrict__ zp, float* __restrict__ out) {

    int tid = threadIdx.x;
    int lane = tid & 63, wv = tid >> 6;
    int wq = wv & 1, half = wv >> 1;
    // XCD-aware swizzle: 2048 blocks % 8 == 0 -> bijective.
    int raw = blockIdx.x;
    int blk = ((raw & 7) << 8) + (raw >> 3);
    int b = blk >> 9, t = blk & 511;
    int h0 = (t >> 5) << 3, w0 = (t & 31) << 2;   // 16 tile-rows x 32 tile-cols

    __shared__ __align__(16) char smem[26064];
    ushort* tile = (ushort*)smem;              // [pos(165) stride 72][cin 64]
    float* offl = (float*)(smem + 23760);      // [px 32][ch 18]

    const float* xb = x + ((long)b << 20);

    // ---- stage halo: 24 chunks x 1 KiB via global_load_lds dwordx4.
    // o4 = chunk*64 + lane in [0,1536); pos = o4/9, slot = o4%9;
    // ty = pos/11 (row), tx = pos%11 (col). slot==8, OOB, pos>=165 -> zero.
    {
        const ushort* xb2 = xbf + ((long)b << 20);
#pragma unroll
        for (int c = 0; c < 6; ++c) {
            int chunk = wv + (c << 2);
            int o4 = (chunk << 6) + lane;           // 0..1535
            int pos = (o4 * 7282) >> 16;            // /9 (exact, o4<=2047)
            int slot = o4 - pos * 9;
            int ty = (pos * 5958) >> 16;            // /11 (exact, pos<=170)
            int tx = pos - ty * 11;
            int y = h0 - 3 + ty, xx = w0 - 3 + tx;
            bool valid = ((unsigned)y < 128u) & ((unsigned)xx < 128u)
                       & (slot < 8) & (pos < 165);
            const ushort* gp = valid
                ? xb2 + (((y << 7) + xx) << 6) + (slot << 3)
                : zp;
            gload16(gp, smem + (chunk << 10));
        }
    }
    __syncthreads();   // waits vmcnt(0) before barrier

    int l15 = lane & 15, lq = lane >> 4;
    int p1 = (wq << 4) + l15;          // this lane's A-row pixel (0..31)
    int plh = p1 >> 2, plw = p1 & 3;   // row 0..7, col 0..3

    // ---- stage 1: offset conv via MFMA, N-split.
    float4x oacc = {0.f, 0.f, 0.f, 0.f};
#pragma unroll
    for (int k2 = 0; k2 < 9; ++k2) {
        int kh = k2 / 3, kw = k2 - kh * 3;
        int pos = (plh + 2 + kh) * 11 + (plw + 2 + kw);
        int abase = pos * 72 + (lq << 3);
#pragma unroll
        for (int hf = 0; hf < 2; ++hf) {
            int kk = k2 * 2 + hf;
            short8x a = *(const short8x*)&tile[abase + hf * 32];
            short8x bo = *(const short8x*)&Bo[(kk * 2 + half) * 512 + (lane << 3)];
            oacc = __builtin_amdgcn_mfma_f32_16x16x32_bf16(a, bo, oacc, 0, 0, 0);
        }
    }
    {   // scatter D (col n = 16*half + l15, row = lq*4+r) + bias -> offl
        int n = (half << 4) + l15;
        if (n < 18) {
            float bo = boff[n];
#pragma unroll
            for (int r = 0; r < 4; ++r) {
                int p = (wq << 4) + (lq << 2) + r;
                offl[p * 18 + n] = oacc[r] + bo;
            }
        }
    }
    __syncthreads();

    // ---- offsets to registers + oob mask (rows clamp 13, cols clamp 9)
    float2 offr[9];
    uint oobmask = 0;
#pragma unroll
    for (int k2 = 0; k2 < 9; ++k2) {
        offr[k2] = *(const float2*)&offl[p1 * 18 + k2 * 2];
        const int kh = k2 / 3, kw = k2 - kh * 3;
        float sy = (float)(plh + 2 + kh) + offr[k2].x;
        float sx = (float)(plw + 2 + kw) + offr[k2].y;
        int by = (int)floorf(sy), bx = (int)floorf(sx);
        bool oob = ((unsigned)by > 13u) | ((unsigned)bx > 9u);
        oobmask |= oob ? (1u << k2) : 0u;
    }

    // ---- stage 2: 9 steps over this wave's cin-half
    float4x acc[4];
#pragma unroll
    for (int nt = 0; nt < 4; ++nt) acc[nt] = (float4x){0.f, 0.f, 0.f, 0.f};

#pragma unroll
    for (int k2 = 0; k2 < 9; ++k2) {
        const int kh = k2 / 3, kw = k2 - kh * 3;
        float sy = (float)(plh + 2 + kh) + offr[k2].x;
        float sx = (float)(plw + 2 + kw) + offr[k2].y;
        float yf = floorf(sy), xf = floorf(sx);
        int by = (int)yf, bx = (int)xf;
        float wy1 = sy - yf, wx1 = sx - xf;
        float wy0 = 1.f - wy1, wx0 = 1.f - wx1;
        float w00 = wy0 * wx0, w01 = wy0 * wx1;
        float w10 = wy1 * wx0, w11 = wy1 * wx1;
        int byc = min(max(by, 0), 13), bxc = min(max(bx, 0), 9);
        int cb = (byc * 11 + bxc) * 72 + (lq << 3) + (half << 5);

        int kk = k2 * 2 + half;
        short8x c00 = *(const short8x*)&tile[cb];
        short8x c01 = *(const short8x*)&tile[cb + 72];
        short8x c10 = *(const short8x*)&tile[cb + 72 * 11];
        short8x c11 = *(const short8x*)&tile[cb + 72 * 12];
        float s[8];
#pragma unroll
        for (int j = 0; j < 8; ++j) {
            s[j] = w00 * bf2f((ushort)c00[j]) + w01 * bf2f((ushort)c01[j])
                 + w10 * bf2f((ushort)c10[j]) + w11 * bf2f((ushort)c11[j]);
        }
        union { short8x v; uint w[4]; } A;
#pragma unroll
        for (int jj = 0; jj < 4; ++jj)
            asm("v_cvt_pk_bf16_f32 %0, %1, %2"
                : "=v"(A.w[jj]) : "v"(s[2 * jj]), "v"(s[2 * jj + 1]));
#pragma unroll
        for (int nt = 0; nt < 4; ++nt) {
            short8x bw = *(const short8x*)&Bd[(kk * 4 + nt) * 512 + (lane << 3)];
            acc[nt] = __builtin_amdgcn_mfma_f32_16x16x32_bf16(A.v, bw, acc[nt], 0, 0, 0);
        }
    }

    // ---- cold exactness pass (own half): out-of-tile samples (~8 sigma).
    if (__any(oobmask != 0)) {
#pragma unroll 1
        for (int k2 = 0; k2 < 9; ++k2) {
            if (!__any((oobmask >> k2) & 1)) continue;
            bool oob = (oobmask >> k2) & 1;
            const int kh = k2 / 3, kw = k2 - kh * 3;
            float2 od = *(const float2*)&offl[p1 * 18 + k2 * 2];
            float sy = (float)(plh + 2 + kh) + od.x;
            float sx = (float)(plw + 2 + kw) + od.y;
            float yf = floorf(sy), xf = floorf(sx);
            int by = (int)yf, bx = (int)xf;
            float wy1 = sy - yf, wx1 = sx - xf;
            float wy0 = 1.f - wy1, wx0 = 1.f - wx1;
            float w00 = wy0 * wx0, w01 = wy0 * wx1;
            float w10 = wy1 * wx0, w11 = wy1 * wx1;
            int byc = min(max(by, 0), 13), bxc = min(max(bx, 0), 9);
            int cb = (byc * 11 + bxc) * 72 + (lq << 3) + (half << 5);
            int y0g = by + h0 - 3, x0g = bx + w0 - 3;
            int y1g = y0g + 1, x1g = x0g + 1;
            float m00 = ((unsigned)y0g < 128u && (unsigned)x0g < 128u) ? w00 : 0.f;
            float m01 = ((unsigned)y0g < 128u && (unsigned)x1g < 128u) ? w01 : 0.f;
            float m10 = ((unsigned)y1g < 128u && (unsigned)x0g < 128u) ? w10 : 0.f;
            float m11 = ((unsigned)y1g < 128u && (unsigned)x1g < 128u) ? w11 : 0.f;
            int y0c = min(max(y0g, 0), 127), y1c = min(max(y1g, 0), 127);
            int x0c = min(max(x0g, 0), 127), x1c = min(max(x1g, 0), 127);
            int i00 = (y0c << 7) + x0c, i01 = (y0c << 7) + x1c;
            int i10 = (y1c << 7) + x0c, i11 = (y1c << 7) + x1c;
            int kk = k2 * 2 + half;
            int cin0 = (half << 5) + (lq << 3);
            short8x c00 = *(const short8x*)&tile[cb];
            short8x c01 = *(const short8x*)&tile[cb + 72];
            short8x c10 = *(const short8x*)&tile[cb + 72 * 11];
            short8x c11 = *(const short8x*)&tile[cb + 72 * 12];
            float d[8];
#pragma unroll
            for (int j = 0; j < 8; ++j) {
                float sl = w00 * bf2f((ushort)c00[j]) + w01 * bf2f((ushort)c01[j])
                         + w10 * bf2f((ushort)c10[j]) + w11 * bf2f((ushort)c11[j]);
                const float* xp = xb + ((long)(cin0 + j) << 14);
                float sg = m00 * xp[i00] + m01 * xp[i01]
                         + m10 * xp[i10] + m11 * xp[i11];
                d[j] = oob ? (sg - sl) : 0.f;
            }
            union { short8x v; ushort u[8]; } A;
#pragma unroll
            for (int j = 0; j < 8; ++j) A.u[j] = f2bf(d[j]);
#pragma unroll
            for (int nt = 0; nt < 4; ++nt) {
                short8x bw = *(const short8x*)&Bd[(kk * 4 + nt) * 512 + (lane << 3)];
                acc[nt] = __builtin_amdgcn_mfma_f32_16x16x32_bf16(A.v, bw, acc[nt], 0, 0, 0);
            }
        }
    }

    // ---- reduce: halves write disjoint red0/red1 (32x65 f32 each), one
    // barrier, store adds. red region overlays dead tile.
    __syncthreads();
    float* redh = (float*)(smem + (half ? 8320 : 0));
#pragma unroll
    for (int nt = 0; nt < 4; ++nt)
#pragma unroll
        for (int r = 0; r < 4; ++r) {
            int p = (wq << 4) + (lq << 2) + r;
            redh[p * 65 + (nt << 4) + l15] = acc[nt][r];
        }
    __syncthreads();

    // ---- store: 256 threads, thread = (cout n, row-pair q); rows 2q,2q+1,
    // each row = 4 floats (full tile width) = 1 float4.
    {
        float* red0 = (float*)smem;
        float* red1 = (float*)(smem + 8320);
        int n = tid >> 2, q = tid & 3;
        float bd = bdef[n];
        float* dst = out + (((long)(b * 64 + n)) << 14) + ((h0 + 2 * q) << 7) + w0;
        float v[8];
#pragma unroll
        for (int c = 0; c < 8; ++c) {
            int p = (2 * q + (c >> 2)) * 4 + (c & 3);
            int idx = p * 65 + n;
            v[c] = red0[idx] + red1[idx] + bd;
        }
        float4x s0 = {v[0], v[1], v[2], v[3]};
        float4x s1 = {v[4], v[5], v[6], v[7]};
        *(float4x*)(dst) = s0;          // row 2q
        *(float4x*)(dst + 128) = s1;    // row 2q+1
    }
}

// ===========================================================================
// FALLBACK PATH (verbatim R12, harness-proven at 110.4 µs; needs ~111 KB ws)
// ===========================================================================

__global__ __launch_bounds__(256) void pack_weights(
    const float* __restrict__ w_def, const float* __restrict__ w_off,
    ushort* __restrict__ Bd, ushort* __restrict__ Bo) {
    int idx = blockIdx.x * 256 + threadIdx.x;
    if (idx < 36864) {
        int i = idx & 7;
        int lane = (idx >> 3) & 63;
        int nt = (idx >> 9) & 3;
        int kk = idx >> 11;
        int n = (nt << 4) + (lane & 15);
        int k2 = kk >> 1;
        int cin = ((kk & 1) << 5) + ((lane >> 4) << 3) + i;
        Bd[idx] = f2bf(w_def[(n * 64 + cin) * 9 + k2]);
    } else if (idx < 36864 + 18432) {
        int d = idx - 36864;
        int i = d & 7;
        int lane = (d >> 3) & 63;
        int nt = (d >> 9) & 1;
        int kk = d >> 10;
        int n = (nt << 4) + (lane & 15);
        int k2 = kk >> 1;
        int cin = ((kk & 1) << 5) + ((lane >> 4) << 3) + i;
        Bo[d] = (n < 18) ? f2bf(w_off[(n * 64 + cin) * 9 + k2]) : (ushort)0;
    }
}

__global__ __launch_bounds__(512, 4) void dcn_fused_fb(
    const float* __restrict__ x, const ushort* __restrict__ Bd,
    const ushort* __restrict__ Bo, const float* __restrict__ boff,
    const float* __restrict__ bdef, float* __restrict__ out) {

    int tid = threadIdx.x;
    int lane = tid & 63, wv = tid >> 6;
    int wq = wv & 3, half = wv >> 2;
    int blk = blockIdx.x;
    int b = blk >> 8, t = blk & 255;
    int h0 = (t >> 4) << 3, w0 = (t & 15) << 3;

    __shared__ __align__(16) char smem[37008];
    ushort* tile = (ushort*)smem;
    float* offl = (float*)(smem + 32400);

    const float* xb = x + ((long)b << 20);

    if (tid < 450) {
        int pos = tid >> 1, ch = (tid & 1) << 5;
        int ty = pos / 15, tx = pos - ty * 15;
        int y = h0 - 3 + ty, xx = w0 - 3 + tx;
        bool valid = ((unsigned)y < 128u) & ((unsigned)xx < 128u);
        int yc = min(max(y, 0), 127), xc = min(max(xx, 0), 127);
        const float* gp = xb + ((long)ch << 14) + (yc << 7) + xc;
        uint4* trow = (uint4*)&tile[pos * 72 + ch];
#pragma unroll
        for (int c8 = 0; c8 < 4; ++c8) {
            const float* g8 = gp + (c8 << 17);
            float v[8];
#pragma unroll
            for (int j = 0; j < 8; ++j) v[j] = valid ? g8[j << 14] : 0.f;
            uint4 d;
            d.x = (uint)f2bf(v[0]) | ((uint)f2bf(v[1]) << 16);
            d.y = (uint)f2bf(v[2]) | ((uint)f2bf(v[3]) << 16);
            d.z = (uint)f2bf(v[4]) | ((uint)f2bf(v[5]) << 16);
            d.w = (uint)f2bf(v[6]) | ((uint)f2bf(v[7]) << 16);
            trow[c8] = d;
        }
    }
    __syncthreads();

    int l15 = lane & 15, lq = lane >> 4;
    int p1 = (wq << 4) + l15;
    int plh = p1 >> 3, plw = p1 & 7;

    float4x oacc = {0.f, 0.f, 0.f, 0.f};
#pragma unroll
    for (int k2 = 0; k2 < 9; ++k2) {
        int kh = k2 / 3, kw = k2 - kh * 3;
        int pos = (plh + 2 + kh) * 15 + (plw + 2 + kw);
        int abase = pos * 72 + (lq << 3);
#pragma unroll
        for (int hf = 0; hf < 2; ++hf) {
            int kk = k2 * 2 + hf;
            short8x a = *(const short8x*)&tile[abase + hf * 32];
            short8x bo = *(const short8x*)&Bo[(kk * 2 + half) * 512 + (lane << 3)];
            oacc = __builtin_amdgcn_mfma_f32_16x16x32_bf16(a, bo, oacc, 0, 0, 0);
        }
    }
    {
        int n = (half << 4) + l15;
        if (n < 18) {
            float bo = boff[n];
#pragma unroll
            for (int r = 0; r < 4; ++r) {
                int p = (wq << 4) + (lq << 2) + r;
                offl[p * 18 + n] = oacc[r] + bo;
            }
        }
    }
    __syncthreads();

    float2 offr[9];
    uint oobmask = 0;
#pragma unroll
    for (int k2 = 0; k2 < 9; ++k2) {
        offr[k2] = *(const float2*)&offl[p1 * 18 + k2 * 2];
        const int kh = k2 / 3, kw = k2 - kh * 3;
        float sy = (float)(plh + 2 + kh) + offr[k2].x;
        float sx = (float)(plw + 2 + kw) + offr[k2].y;
        int by = (int)floorf(sy), bx = (int)floorf(sx);
        bool oob = ((unsigned)by > 13u) | ((unsigned)bx > 13u);
        oobmask |= oob ? (1u << k2) : 0u;
    }

    float4x acc[4];
#pragma unroll
    for (int nt = 0; nt < 4; ++nt) acc[nt] = (float4x){0.f, 0.f, 0.f, 0.f};

#pragma unroll
    for (int k2 = 0; k2 < 9; ++k2) {
        const int kh = k2 / 3, kw = k2 - kh * 3;
        float sy = (float)(plh + 2 + kh) + offr[k2].x;
        float sx = (float)(plw + 2 + kw) + offr[k2].y;
        float yf = floorf(sy), xf = floorf(sx);
        int by = (int)yf, bx = (int)xf;
        float wy1 = sy - yf, wx1 = sx - xf;
        float wy0 = 1.f - wy1, wx0 = 1.f - wx1;
        float w00 = wy0 * wx0, w01 = wy0 * wx1;
        float w10 = wy1 * wx0, w11 = wy1 * wx1;
        int byc = min(max(by, 0), 13), bxc = min(max(bx, 0), 13);
        int cb = (byc * 15 + bxc) * 72 + (lq << 3) + (half << 5);

        int kk = k2 * 2 + half;
        short8x c00 = *(const short8x*)&tile[cb];
        short8x c01 = *(const short8x*)&tile[cb + 72];
        short8x c10 = *(const short8x*)&tile[cb + 72 * 15];
        short8x c11 = *(const short8x*)&tile[cb + 72 * 16];
        float s[8];
#pragma unroll
        for (int j = 0; j < 8; ++j) {
            s[j] = w00 * bf2f((ushort)c00[j]) + w01 * bf2f((ushort)c01[j])
                 + w10 * bf2f((ushort)c10[j]) + w11 * bf2f((ushort)c11[j]);
        }
        union { short8x v; ushort u[8]; } A;
#pragma unroll
        for (int j = 0; j < 8; ++j) A.u[j] = f2bf(s[j]);
#pragma unroll
        for (int nt = 0; nt < 4; ++nt) {
            short8x bw = *(const short8x*)&Bd[(kk * 4 + nt) * 512 + (lane << 3)];
            acc[nt] = __builtin_amdgcn_mfma_f32_16x16x32_bf16(A.v, bw, acc[nt], 0, 0, 0);
        }
    }

    if (__any(oobmask != 0)) {
#pragma unroll 1
        for (int k2 = 0; k2 < 9; ++k2) {
            if (!__any((oobmask >> k2) & 1)) continue;
            bool oob = (oobmask >> k2) & 1;
            const int kh = k2 / 3, kw = k2 - kh * 3;
            float2 od = *(const float2*)&offl[p1 * 18 + k2 * 2];
            float sy = (float)(plh + 2 + kh) + od.x;
            float sx = (float)(plw + 2 + kw) + od.y;
            float yf = floorf(sy), xf = floorf(sx);
            int by = (int)yf, bx = (int)xf;
            float wy1 = sy - yf, wx1 = sx - xf;
            float wy0 = 1.f - wy1, wx0 = 1.f - wx1;
            float w00 = wy0 * wx0, w01 = wy0 * wx1;
            float w10 = wy1 * wx0, w11 = wy1 * wx1;
            int byc = min(max(by, 0), 13), bxc = min(max(bx, 0), 13);
            int cb = (byc * 15 + bxc) * 72 + (lq << 3) + (half << 5);
            int y0g = by + h0 - 3, x0g = bx + w0 - 3;
            int y1g = y0g + 1, x1g = x0g + 1;
            float m00 = ((unsigned)y0g < 128u && (unsigned)x0g < 128u) ? w00 : 0.f;
            float m01 = ((unsigned)y0g < 128u && (unsigned)x1g < 128u) ? w01 : 0.f;
            float m10 = ((unsigned)y1g < 128u && (unsigned)x0g < 128u) ? w10 : 0.f;
            float m11 = ((unsigned)y1g < 128u && (unsigned)x1g < 128u) ? w11 : 0.f;
            int y0c = min(max(y0g, 0), 127), y1c = min(max(y1g, 0), 127);
            int x0c = min(max(x0g, 0), 127), x1c = min(max(x1g, 0), 127);
            int i00 = (y0c << 7) + x0c, i01 = (y0c << 7) + x1c;
            int i10 = (y1c << 7) + x0c, i11 = (y1c << 7) + x1c;
            int kk = k2 * 2 + half;
            int cin0 = (half << 5) + (lq << 3);
            short8x c00 = *(const short8x*)&tile[cb];
            short8x c01 = *(const short8x*)&tile[cb + 72];
            short8x c10 = *(const short8x*)&tile[cb + 72 * 15];
            short8x c11 = *(const short8x*)&tile[cb + 72 * 16];
            float d[8];
#pragma unroll
            for (int j = 0; j < 8; ++j) {
                float sl = w00 * bf2f((ushort)c00[j]) + w01 * bf2f((ushort)c01[j])
                         + w10 * bf2f((ushort)c10[j]) + w11 * bf2f((ushort)c11[j]);
                const float* xp = xb + ((long)(cin0 + j) << 14);
                float sg = m00 * xp[i00] + m01 * xp[i01]
                         + m10 * xp[i10] + m11 * xp[i11];
                d[j] = oob ? (sg - sl) : 0.f;
            }
            union { short8x v; ushort u[8]; } A;
#pragma unroll
            for (int j = 0; j < 8; ++j) A.u[j] = f2bf(d[j]);
#pragma unroll
            for (int nt = 0; nt < 4; ++nt) {
                short8x bw = *(const short8x*)&Bd[(kk * 4 + nt) * 512 + (lane << 3)];
                acc[nt] = __builtin_amdgcn_mfma_f32_16x16x32_bf16(A.v, bw, acc[nt], 0, 0, 0);
            }
        }
    }

    __syncthreads();
    float* red = (float*)smem;
    if (half == 1) {
#pragma unroll
        for (int nt = 0; nt < 4; ++nt)
#pragma unroll
            for (int r = 0; r < 4; ++r) {
                int p = (wq << 4) + (lq << 2) + r;
                red[p * 65 + (nt << 4) + l15] = acc[nt][r];
            }
    }
    __syncthreads();
    if (half == 0) {
#pragma unroll
        for (int nt = 0; nt < 4; ++nt)
#pragma unroll
            for (int r = 0; r < 4; ++r) {
                int p = (wq << 4) + (lq << 2) + r;
                red[p * 65 + (nt << 4) + l15] += acc[nt][r];
            }
    }
    __syncthreads();

    {
        int n = tid >> 3, q = tid & 7;
        float bd = bdef[n];
        float* dst = out + (((long)(b * 64 + n)) << 14) + ((h0 + q) << 7) + w0;
        float v[8];
#pragma unroll
        for (int c = 0; c < 8; ++c) v[c] = red[(q * 8 + c) * 65 + n] + bd;
        float4x s0 = {v[0], v[1], v[2], v[3]};
        float4x s1 = {v[4], v[5], v[6], v[7]};
        *(float4x*)(dst) = s0;
        *(float4x*)(dst + 4) = s1;
    }
}

// ---------------------------------------------------------------------------
extern "C" void kernel_launch(void* const* d_in, const int* in_sizes, int n_in,
                              void* d_out, int out_size, void* d_ws, size_t ws_size,
                              hipStream_t stream) {
    const float* x     = (const float*)d_in[0];  // (4,64,128,128)
    const float* w_off = (const float*)d_in[1];  // (18,64,3,3)
    const float* b_off = (const float*)d_in[2];  // (18,)
    const float* w_def = (const float*)d_in[3];  // (64,64,3,3)
    const float* b_def = (const float*)d_in[4];  // (64,)
    float* out = (float*)d_out;                  // (4,64,128,128)

    const size_t NEED = 8388608ull + 73728ull + 36864ull + 16ull;
    if (ws_size >= NEED) {
        // fast path: xbf 8 MiB | Bd 73728 B | Bo 36864 B | zero page 16 B
        ushort* xbf = (ushort*)d_ws;                          // 4*16384*64 bf16
        ushort* Bd  = (ushort*)((char*)d_ws + 8388608);       // 36864 bf16
        ushort* Bo  = Bd + 36864;                             // 18432 bf16
        uint*   zp  = (uint*)((char*)d_ws + 8388608 + 73728 + 36864);
        hipLaunchKernelGGL(pack_all, dim3(944), dim3(128), 0, stream,
                           x, w_def, w_off, xbf, Bd, Bo, zp);
        hipLaunchKernelGGL(dcn_fused, dim3(2048), dim3(256), 0, stream,
                           x, xbf, Bd, Bo, b_off, b_def, (const ushort*)zp, out);
    } else {
        // fallback: verbatim R12 (proven)
        ushort* Bd = (ushort*)d_ws;                  // 36864 bf16 = 73728 B
        ushort* Bo = Bd + 36864;                     // 18432 bf16 = 36864 B
        hipLaunchKernelGGL(pack_weights, dim3(216), dim3(256), 0, stream,
                           w_def, w_off, Bd, Bo);
        hipLaunchKernelGGL(dcn_fused_fb, dim3(1024), dim3(512), 0, stream,
                           x, Bd, Bo, b_off, b_def, out);
    }
}